// Round 11
// baseline (248.806 us; speedup 1.0000x reference)
//
#include <hip/hip_runtime.h>
#include <hip/hip_bf16.h>

#define BB 8
#define CC 512
#define TT 1024
#define HH 8
#define HD 64
#define CLIPW 4
#define NCOUT 512

using bf16 = __hip_bfloat16;
typedef __bf16 bf16x8_t __attribute__((ext_vector_type(8)));
typedef __bf16 bf16x4_t __attribute__((ext_vector_type(4)));
typedef float f32x4_t __attribute__((ext_vector_type(4)));

__device__ __forceinline__ float bf2f(bf16 v) {
  return __uint_as_float(((unsigned int)*(unsigned short*)&v) << 16);
}

// ===========================================================================
// GEMM kernels (unchanged; ~66 us combined)
// ===========================================================================
__global__ __launch_bounds__(256) void gemm_qkv(
    const float* __restrict__ X,
    const float* __restrict__ Wq, const float* __restrict__ bq,
    const float* __restrict__ Wk, const float* __restrict__ bk,
    const float* __restrict__ Wv, const float* __restrict__ bv,
    bf16* __restrict__ qw, bf16* __restrict__ kw, bf16* __restrict__ vtw) {
  __shared__ __align__(16) char smem[2 * 64 * 72 * 2];
  __bf16* Ws = (__bf16*)smem;
  __bf16* Xs = (__bf16*)(smem + 64 * 72 * 2);

  const int y  = blockIdx.y;
  const int m  = y >> 3;
  const int o0 = (y & 7) * 64;
  const int t0 = blockIdx.x * 64;
  const int b  = blockIdx.z;
  const float* W    = (m == 0) ? Wq : (m == 1) ? Wk : Wv;
  const float* bias = (m == 0) ? bq : (m == 1) ? bk : bv;

  const int tid = threadIdx.x;
  const int w = tid >> 6, l = tid & 63, g = l >> 4, sl = l & 15;
  const int wr = w >> 1, wc = w & 1;

  f32x4_t acc[2][2] = {};
  for (int c0 = 0; c0 < CC; c0 += 64) {
    {
      const int oi = tid >> 4, c4 = (tid & 15) * 4;
#pragma unroll
      for (int op = 0; op < 4; ++op) {
        const int o = op * 16 + oi;
        const float4 w4 = *(const float4*)&W[(size_t)(o0 + o) * CC + c0 + c4];
        bf16x4_t p;
        p[0] = (__bf16)w4.x; p[1] = (__bf16)w4.y;
        p[2] = (__bf16)w4.z; p[3] = (__bf16)w4.w;
        *(bf16x4_t*)&Ws[o * 72 + c4] = p;
      }
    }
    {
      const int t4 = (tid & 15) * 4, ci = tid >> 4;
#pragma unroll
      for (int cp = 0; cp < 4; ++cp) {
        const int c = cp * 16 + ci;
        const float4 x4 = *(const float4*)&X[((size_t)b * CC + c0 + c) * TT + t0 + t4];
        Xs[(t4 + 0) * 72 + c] = (__bf16)x4.x;
        Xs[(t4 + 1) * 72 + c] = (__bf16)x4.y;
        Xs[(t4 + 2) * 72 + c] = (__bf16)x4.z;
        Xs[(t4 + 3) * 72 + c] = (__bf16)x4.w;
      }
    }
    __syncthreads();
#pragma unroll
    for (int kk = 0; kk < 2; ++kk) {
      bf16x8_t a[2], bb[2];
#pragma unroll
      for (int mm = 0; mm < 2; ++mm)
        a[mm] = *(const bf16x8_t*)&Ws[(wr * 32 + mm * 16 + sl) * 72 + kk * 32 + g * 8];
#pragma unroll
      for (int nn = 0; nn < 2; ++nn)
        bb[nn] = *(const bf16x8_t*)&Xs[(wc * 32 + nn * 16 + sl) * 72 + kk * 32 + g * 8];
#pragma unroll
      for (int mm = 0; mm < 2; ++mm)
#pragma unroll
        for (int nn = 0; nn < 2; ++nn)
          acc[mm][nn] = __builtin_amdgcn_mfma_f32_16x16x32_bf16(a[mm], bb[nn], acc[mm][nn], 0, 0, 0);
    }
    __syncthreads();
  }

  float* Cs = (float*)smem;
#pragma unroll
  for (int mm = 0; mm < 2; ++mm)
#pragma unroll
    for (int nn = 0; nn < 2; ++nn)
#pragma unroll
      for (int r = 0; r < 4; ++r)
        Cs[(wr * 32 + mm * 16 + 4 * g + r) * 68 + wc * 32 + nn * 16 + sl] = acc[mm][nn][r];
  __syncthreads();

  if (m < 2) {
    bf16* dst = (m == 0) ? qw : kw;
    const int hh2 = o0 >> 6;
    const int t = tid >> 2, oq = tid & 3;
    bf16x8_t p0, p1;
#pragma unroll
    for (int i = 0; i < 8; ++i) {
      p0[i] = (__bf16)(Cs[(oq * 16 + i) * 68 + t] + bias[o0 + oq * 16 + i]);
      p1[i] = (__bf16)(Cs[(oq * 16 + 8 + i) * 68 + t] + bias[o0 + oq * 16 + 8 + i]);
    }
    bf16* dp = dst + (((size_t)b * HH + hh2) * TT + t0 + t) * HD + oq * 16;
    *(bf16x8_t*)dp = p0;
    *(bf16x8_t*)(dp + 8) = p1;
  } else {
    const int o = tid >> 2, tq = tid & 3;
    const float bv_ = bias[o0 + o];
    bf16x8_t p0, p1;
#pragma unroll
    for (int i = 0; i < 8; ++i) {
      p0[i] = (__bf16)(Cs[o * 68 + tq * 16 + i] + bv_);
      p1[i] = (__bf16)(Cs[o * 68 + tq * 16 + 8 + i] + bv_);
    }
    bf16* dp = vtw + ((size_t)b * CC + o0 + o) * TT + t0 + tq * 16;
    *(bf16x8_t*)dp = p0;
    *(bf16x8_t*)(dp + 8) = p1;
  }
}

__global__ __launch_bounds__(256) void gemm_out(
    const bf16* __restrict__ S, const float* __restrict__ Wp,
    const float* __restrict__ bp, float* __restrict__ out) {
  __shared__ __align__(16) char smem[2 * 64 * 72 * 2];
  __bf16* Ws = (__bf16*)smem;
  __bf16* Xs = (__bf16*)(smem + 64 * 72 * 2);

  const int o0 = blockIdx.y * 64;
  const int t0 = blockIdx.x * 64;
  const int b  = blockIdx.z;
  const int tid = threadIdx.x;
  const int w = tid >> 6, l = tid & 63, g = l >> 4, sl = l & 15;
  const int wr = w >> 1, wc = w & 1;

  f32x4_t acc[2][2] = {};
  for (int c0 = 0; c0 < CC; c0 += 64) {
    {
      const int oi = tid >> 4, c4 = (tid & 15) * 4;
#pragma unroll
      for (int op = 0; op < 4; ++op) {
        const int o = op * 16 + oi;
        const float4 w4 = *(const float4*)&Wp[(size_t)(o0 + o) * CC + c0 + c4];
        bf16x4_t p;
        p[0] = (__bf16)w4.x; p[1] = (__bf16)w4.y;
        p[2] = (__bf16)w4.z; p[3] = (__bf16)w4.w;
        *(bf16x4_t*)&Ws[o * 72 + c4] = p;
      }
    }
    {
      const int t4 = (tid & 15) * 4, ci = tid >> 4;
#pragma unroll
      for (int cp = 0; cp < 4; ++cp) {
        const int c = cp * 16 + ci;
        const bf16x4_t x4 = *(const bf16x4_t*)&S[((size_t)b * CC + c0 + c) * TT + t0 + t4];
        Xs[(t4 + 0) * 72 + c] = x4[0];
        Xs[(t4 + 1) * 72 + c] = x4[1];
        Xs[(t4 + 2) * 72 + c] = x4[2];
        Xs[(t4 + 3) * 72 + c] = x4[3];
      }
    }
    __syncthreads();
#pragma unroll
    for (int kk = 0; kk < 2; ++kk) {
      bf16x8_t a[2], bb[2];
#pragma unroll
      for (int mm = 0; mm < 2; ++mm)
        a[mm] = *(const bf16x8_t*)&Ws[(wr * 32 + mm * 16 + sl) * 72 + kk * 32 + g * 8];
#pragma unroll
      for (int nn = 0; nn < 2; ++nn)
        bb[nn] = *(const bf16x8_t*)&Xs[(wc * 32 + nn * 16 + sl) * 72 + kk * 32 + g * 8];
#pragma unroll
      for (int mm = 0; mm < 2; ++mm)
#pragma unroll
        for (int nn = 0; nn < 2; ++nn)
          acc[mm][nn] = __builtin_amdgcn_mfma_f32_16x16x32_bf16(a[mm], bb[nn], acc[mm][nn], 0, 0, 0);
    }
    __syncthreads();
  }

  float* Cs = (float*)smem;
#pragma unroll
  for (int mm = 0; mm < 2; ++mm)
#pragma unroll
    for (int nn = 0; nn < 2; ++nn)
#pragma unroll
      for (int r = 0; r < 4; ++r)
        Cs[(wr * 32 + mm * 16 + 4 * g + r) * 68 + wc * 32 + nn * 16 + sl] = acc[mm][nn][r];
  __syncthreads();

  const int o = tid >> 2, tq = tid & 3;
  const float bv_ = bp[o0 + o];
  float* dp = out + ((size_t)b * NCOUT + o0 + o) * TT + t0 + tq * 16;
#pragma unroll
  for (int i4 = 0; i4 < 4; ++i4) {
    f32x4_t v = *(const f32x4_t*)&Cs[o * 68 + tq * 16 + i4 * 4];
    v[0] += bv_; v[1] += bv_; v[2] += bv_; v[3] += bv_;
    *(f32x4_t*)(dp + i4 * 4) = v;
  }
}

// ===========================================================================
// attn v8 = v7 + explicit register software-pipelining:
//   pass1: 3-deep K prefetch; pass2: 2-deep V + 2-deep pb(ds_read) prefetch,
//   slot0 issued before the lsum barrier. All buffers statically indexed.
// ===========================================================================
__global__ __launch_bounds__(256, 4) void attn_v8(
    const bf16* __restrict__ qw, const bf16* __restrict__ kw,
    const bf16* __restrict__ vtw,
    const float* __restrict__ wK, const float* __restrict__ wV,
    float* __restrict__ align_out, bf16* __restrict__ attnw) {
  const int fi   = blockIdx.x;
  const int xcd  = fi & 7;
  const int k2   = fi >> 3;
  const int bh   = ((k2 >> 6) << 3) + xcd;
  const int qblk = k2 & 63;
  const int b = bh >> 3, h = bh & 7;
  const int q0 = qblk * 16;

  const int tid = threadIdx.x;
  const int w = tid >> 6, l = tid & 63, g = l >> 4, ql = l & 15;
  const int qabs  = q0 + ql;
  const int sbase = w * 256;

  // LDS: eL [64 rows][264 bf16] (33792 B) | bandv 3072 | bandP 2304 | red 256
  __shared__ __align__(16) char smem[39424];
  __bf16* eL    = (__bf16*)smem;
  float* bandv  = (float*)(smem + 33792);
  float* bandP  = (float*)(smem + 36864);
  float* redbuf = (float*)(smem + 39168);
  float* obuf   = (float*)smem;                 // overlay after barrier (17408 B)
  float* stg    = (float*)(smem + 17408);       // overlay epilogue (4352 B)

  for (int i = tid; i < 576; i += 256) bandP[i] = 0.f;

  const bf16* qb = qw + ((size_t)bh * TT + qabs) * HD + g * 8;
  const bf16x8_t qa0 = *(const bf16x8_t*)qb;
  const bf16x8_t qa1 = *(const bf16x8_t*)(qb + 32);

  // band-K: D[j][q] via mfma(A=wK rows, B=Q cols)
  {
    const int j = (ql < 9) ? ql : 0;
    const float* wkr = wK + j * HD + g * 8;
    const f32x4_t w0 = *(const f32x4_t*)wkr;
    const f32x4_t w1 = *(const f32x4_t*)(wkr + 4);
    const f32x4_t w2 = *(const f32x4_t*)(wkr + 32);
    const f32x4_t w3 = *(const f32x4_t*)(wkr + 36);
    bf16x8_t ka0, ka1;
#pragma unroll
    for (int i = 0; i < 4; ++i) {
      ka0[i] = (__bf16)w0[i]; ka0[4 + i] = (__bf16)w1[i];
      ka1[i] = (__bf16)w2[i]; ka1[4 + i] = (__bf16)w3[i];
    }
    f32x4_t bacc = {0.f, 0.f, 0.f, 0.f};
    bacc = __builtin_amdgcn_mfma_f32_16x16x32_bf16(ka0, qa0, bacc, 0, 0, 0);
    bacc = __builtin_amdgcn_mfma_f32_16x16x32_bf16(ka1, qa1, bacc, 0, 0, 0);
#pragma unroll
    for (int r = 0; r < 4; ++r)
      if (4 * g + r < 9) bandv[(w * 16 + ql) * 12 + 4 * g + r] = bacc[r];
  }

  // ---- pass 1: QK + exp; 3-deep K prefetch; stash regs + k-major eL ----
  float ls = 0.f;
  bf16x4_t stash[16];
  const int erow = (w * 16 + ql) * 264;
  const bf16* kwb = kw + ((size_t)bh * TT + ql) * HD + g * 8;   // + (sbase+st*16)*HD

  bf16x8_t kb0[3], kb1[3];
#pragma unroll
  for (int st = 0; st < 3; ++st) {
    const bf16* kb = kwb + (size_t)(sbase + st * 16) * HD;
    kb0[st] = *(const bf16x8_t*)kb;
    kb1[st] = *(const bf16x8_t*)(kb + 32);
  }

#pragma unroll
  for (int st = 0; st < 16; ++st) {
    const bf16x8_t k0 = kb0[st % 3];
    const bf16x8_t k1 = kb1[st % 3];
    if (st + 3 < 16) {
      const bf16* kb = kwb + (size_t)(sbase + (st + 3) * 16) * HD;
      kb0[st % 3] = *(const bf16x8_t*)kb;
      kb1[st % 3] = *(const bf16x8_t*)(kb + 32);
    }
    f32x4_t a = {0.f, 0.f, 0.f, 0.f};
    a = __builtin_amdgcn_mfma_f32_16x16x32_bf16(k0, qa0, a, 0, 0, 0);
    a = __builtin_amdgcn_mfma_f32_16x16x32_bf16(k1, qa1, a, 0, 0, 0);
    const int s0t = sbase + st * 16;
    const bool near = (s0t + 15 >= q0 - CLIPW) && (s0t <= q0 + 15 + CLIPW);
#pragma unroll
    for (int r = 0; r < 4; ++r) {
      float x = a[r];
      if (near) {
        const int delta = s0t + 4 * g + r - qabs;
        if ((unsigned)(delta + CLIPW) <= 2 * CLIPW)
          x += bandv[(w * 16 + ql) * 12 + delta + CLIPW];
      }
      const float e = __expf(x * 0.125f);
      stash[st][r] = (__bf16)e;
      ls += e;
    }
    *(bf16x4_t*)&eL[erow + st * 16 + 4 * g] = stash[st];
  }

  // prefetch pass-2 slot 0 (V + pb) before the barrier hides their latency
  const bf16* vwb = vtw + ((size_t)bh * HD + ql) * TT + sbase + g * 8;  // + dt*16*TT + i2*32
  bf16x8_t vb0_0 = *(const bf16x8_t*)(vwb);
  bf16x8_t vb0_1 = *(const bf16x8_t*)(vwb + (size_t)16 * TT);
  bf16x8_t vb0_2 = *(const bf16x8_t*)(vwb + (size_t)32 * TT);
  bf16x8_t vb0_3 = *(const bf16x8_t*)(vwb + (size_t)48 * TT);
  bf16x8_t pb0 = *(const bf16x8_t*)&eL[erow + 8 * g];

  ls += __shfl_xor(ls, 16);
  ls += __shfl_xor(ls, 32);
  if (l < 16) redbuf[w * 16 + ql] = ls;
  __syncthreads();
  const float inv = 1.0f / (redbuf[ql] + redbuf[16 + ql] + redbuf[32 + ql] + redbuf[48 + ql]);

  // ---- pass 2: PV + align stores; 2-deep V/pb pipeline ----
  f32x4_t oacc[4] = {};
  bf16x8_t vbA[4] = {vb0_0, vb0_1, vb0_2, vb0_3};
  bf16x8_t vbB[4];
  bf16x8_t pbv[2];
  pbv[0] = pb0;
#pragma unroll
  for (int i2 = 0; i2 < 8; ++i2) {
    // prefetch slot for i2+1
    if (i2 + 1 < 8) {
      pbv[(i2 + 1) & 1] = *(const bf16x8_t*)&eL[erow + (i2 + 1) * 32 + 8 * g];
      const bf16* vp = vwb + (i2 + 1) * 32;
      if ((i2 & 1) == 0) {
        vbB[0] = *(const bf16x8_t*)(vp);
        vbB[1] = *(const bf16x8_t*)(vp + (size_t)16 * TT);
        vbB[2] = *(const bf16x8_t*)(vp + (size_t)32 * TT);
        vbB[3] = *(const bf16x8_t*)(vp + (size_t)48 * TT);
      } else {
        vbA[0] = *(const bf16x8_t*)(vp);
        vbA[1] = *(const bf16x8_t*)(vp + (size_t)16 * TT);
        vbA[2] = *(const bf16x8_t*)(vp + (size_t)32 * TT);
        vbA[3] = *(const bf16x8_t*)(vp + (size_t)48 * TT);
      }
    }
    const bf16x8_t pb = pbv[i2 & 1];
    if ((i2 & 1) == 0) {
#pragma unroll
      for (int dt = 0; dt < 4; ++dt)
        oacc[dt] = __builtin_amdgcn_mfma_f32_16x16x32_bf16(vbA[dt], pb, oacc[dt], 0, 0, 0);
    } else {
#pragma unroll
      for (int dt = 0; dt < 4; ++dt)
        oacc[dt] = __builtin_amdgcn_mfma_f32_16x16x32_bf16(vbB[dt], pb, oacc[dt], 0, 0, 0);
    }
#pragma unroll
    for (int h2 = 0; h2 < 2; ++h2) {
      const int st = i2 * 2 + h2;
      const int s0t = sbase + st * 16;
      const bool near = (s0t + 15 >= q0 - CLIPW) && (s0t <= q0 + 15 + CLIPW);
      f32x4_t p4;
#pragma unroll
      for (int r = 0; r < 4; ++r) {
        const float p = (float)stash[st][r] * inv;
        p4[r] = p;
        if (near) {
          const int delta = s0t + 4 * g + r - qabs;
          if ((unsigned)(delta + CLIPW) <= 2 * CLIPW)
            bandP[ql * 36 + delta + CLIPW] = p;
        }
      }
      float* gp = align_out + ((size_t)bh * TT + qabs) * TT + s0t + 4 * g;
      *(f32x4_t*)gp = p4;
    }
  }
  // scale O by inv (per-lane q is fixed = ql)
#pragma unroll
  for (int dt = 0; dt < 4; ++dt) {
    oacc[dt][0] *= inv; oacc[dt][1] *= inv;
    oacc[dt][2] *= inv; oacc[dt][3] *= inv;
  }

  // ---- all eL reads must complete block-wide before obuf overlays eL ----
  __syncthreads();

#pragma unroll
  for (int dt = 0; dt < 4; ++dt)
    *(f32x4_t*)&obuf[w * 1088 + ql * 68 + dt * 16 + 4 * g] = oacc[dt];
  __syncthreads();

  // ---- epilogue (wave 0): reduce + band-V MFMA + store attn ----
  if (w == 0) {
    f32x4_t osum[4];
#pragma unroll
    for (int dt = 0; dt < 4; ++dt) {
      const int off = ql * 68 + dt * 16 + 4 * g;
      osum[dt] = *(const f32x4_t*)&obuf[off] + *(const f32x4_t*)&obuf[1088 + off] +
                 *(const f32x4_t*)&obuf[2176 + off] + *(const f32x4_t*)&obuf[3264 + off];
    }
    const f32x4_t b0 = *(const f32x4_t*)&bandP[ql * 36 + g * 8];
    const f32x4_t b1 = *(const f32x4_t*)&bandP[ql * 36 + g * 8 + 4];
    bf16x8_t pbb;
#pragma unroll
    for (int i = 0; i < 4; ++i) {
      pbb[i] = (__bf16)b0[i];
      pbb[4 + i] = (__bf16)b1[i];
    }
#pragma unroll
    for (int dt = 0; dt < 4; ++dt) {
      bf16x8_t wa;
#pragma unroll
      for (int jj = 0; jj < 8; ++jj) {
        const int j = g * 8 + jj;
        wa[jj] = (__bf16)((j < 9) ? wV[j * HD + dt * 16 + ql] : 0.f);
      }
      osum[dt] = __builtin_amdgcn_mfma_f32_16x16x32_bf16(wa, pbb, osum[dt], 0, 0, 0);
    }
#pragma unroll
    for (int dt = 0; dt < 4; ++dt)
#pragma unroll
      for (int r = 0; r < 4; ++r)
        stg[(dt * 16 + 4 * g + r) * 17 + ql] = osum[dt][r];
    bf16x8_t o0, o1;
#pragma unroll
    for (int i = 0; i < 8; ++i) {
      o0[i] = (__bf16)stg[l * 17 + i];
      o1[i] = (__bf16)stg[l * 17 + 8 + i];
    }
    bf16* dp = attnw + ((size_t)b * CC + h * HD + l) * TT + q0;
    *(bf16x8_t*)dp = o0;
    *(bf16x8_t*)(dp + 8) = o1;
  }
}

extern "C" void kernel_launch(void* const* d_in, const int* in_sizes, int n_in,
                              void* d_out, int out_size, void* d_ws, size_t ws_size,
                              hipStream_t stream) {
  const float* X  = (const float*)d_in[0];
  const float* Wq = (const float*)d_in[1];
  const float* bq = (const float*)d_in[2];
  const float* Wk = (const float*)d_in[3];
  const float* bk = (const float*)d_in[4];
  const float* Wv = (const float*)d_in[5];
  const float* bv = (const float*)d_in[6];
  const float* Wp = (const float*)d_in[7];
  const float* bp = (const float*)d_in[8];
  const float* wK = (const float*)d_in[9];
  const float* wV = (const float*)d_in[10];

  float* out       = (float*)d_out;
  float* align_out = out + (size_t)BB * NCOUT * TT;

  const size_t SZ = (size_t)BB * HH * TT * HD;
  bf16* qw    = (bf16*)d_ws;
  bf16* kw    = qw + SZ;
  bf16* vtw   = qw + 2 * SZ;
  bf16* attnw = qw + 3 * SZ;

  gemm_qkv<<<dim3(TT / 64, 24, BB), 256, 0, stream>>>(
      X, Wq, bq, Wk, bk, Wv, bv, qw, kw, vtw);
  attn_v8<<<dim3(4096), 256, 0, stream>>>(
      qw, kw, vtw, wK, wV, align_out, attnw);
  gemm_out<<<dim3(TT / 64, NCOUT / 64, BB), 256, 0, stream>>>(
      attnw, Wp, bp, out);
}

// Round 12
// 201.892 us; speedup vs baseline: 1.2324x; 1.2324x over previous
//
#include <hip/hip_runtime.h>
#include <hip/hip_bf16.h>

#define BB 8
#define CC 512
#define TT 1024
#define HH 8
#define HD 64
#define CLIPW 4
#define NCOUT 512

using bf16 = __hip_bfloat16;
typedef __bf16 bf16x8_t __attribute__((ext_vector_type(8)));
typedef __bf16 bf16x4_t __attribute__((ext_vector_type(4)));
typedef float f32x4_t __attribute__((ext_vector_type(4)));

__device__ __forceinline__ float bf2f(bf16 v) {
  return __uint_as_float(((unsigned int)*(unsigned short*)&v) << 16);
}

// ===========================================================================
// K1: fused q/k/v projection. Q -> row-major [bh][t][d].
// K -> frag layout kfrag[bh][st][half][lane][8]   (st = t/16, half = k/32)
// V -> frag layout vfrag[bh][i2][dt][lane][8]     (i2 = s/32, dt = d/16)
// so attn loads are contiguous 1KB per wave instruction.
// ===========================================================================
__global__ __launch_bounds__(256) void gemm_qkv(
    const float* __restrict__ X,
    const float* __restrict__ Wq, const float* __restrict__ bq,
    const float* __restrict__ Wk, const float* __restrict__ bk,
    const float* __restrict__ Wv, const float* __restrict__ bv,
    bf16* __restrict__ qw, bf16* __restrict__ kfrag, bf16* __restrict__ vfrag) {
  __shared__ __align__(16) char smem[2 * 64 * 72 * 2];
  __bf16* Ws = (__bf16*)smem;
  __bf16* Xs = (__bf16*)(smem + 64 * 72 * 2);

  const int y  = blockIdx.y;
  const int m  = y >> 3;
  const int o0 = (y & 7) * 64;
  const int t0 = blockIdx.x * 64;
  const int b  = blockIdx.z;
  const float* W    = (m == 0) ? Wq : (m == 1) ? Wk : Wv;
  const float* bias = (m == 0) ? bq : (m == 1) ? bk : bv;

  const int tid = threadIdx.x;
  const int w = tid >> 6, l = tid & 63, g = l >> 4, sl = l & 15;
  const int wr = w >> 1, wc = w & 1;

  f32x4_t acc[2][2] = {};
  for (int c0 = 0; c0 < CC; c0 += 64) {
    {
      const int oi = tid >> 4, c4 = (tid & 15) * 4;
#pragma unroll
      for (int op = 0; op < 4; ++op) {
        const int o = op * 16 + oi;
        const float4 w4 = *(const float4*)&W[(size_t)(o0 + o) * CC + c0 + c4];
        bf16x4_t p;
        p[0] = (__bf16)w4.x; p[1] = (__bf16)w4.y;
        p[2] = (__bf16)w4.z; p[3] = (__bf16)w4.w;
        *(bf16x4_t*)&Ws[o * 72 + c4] = p;
      }
    }
    {
      const int t4 = (tid & 15) * 4, ci = tid >> 4;
#pragma unroll
      for (int cp = 0; cp < 4; ++cp) {
        const int c = cp * 16 + ci;
        const float4 x4 = *(const float4*)&X[((size_t)b * CC + c0 + c) * TT + t0 + t4];
        Xs[(t4 + 0) * 72 + c] = (__bf16)x4.x;
        Xs[(t4 + 1) * 72 + c] = (__bf16)x4.y;
        Xs[(t4 + 2) * 72 + c] = (__bf16)x4.z;
        Xs[(t4 + 3) * 72 + c] = (__bf16)x4.w;
      }
    }
    __syncthreads();
#pragma unroll
    for (int kk = 0; kk < 2; ++kk) {
      bf16x8_t a[2], bb[2];
#pragma unroll
      for (int mm = 0; mm < 2; ++mm)
        a[mm] = *(const bf16x8_t*)&Ws[(wr * 32 + mm * 16 + sl) * 72 + kk * 32 + g * 8];
#pragma unroll
      for (int nn = 0; nn < 2; ++nn)
        bb[nn] = *(const bf16x8_t*)&Xs[(wc * 32 + nn * 16 + sl) * 72 + kk * 32 + g * 8];
#pragma unroll
      for (int mm = 0; mm < 2; ++mm)
#pragma unroll
        for (int nn = 0; nn < 2; ++nn)
          acc[mm][nn] = __builtin_amdgcn_mfma_f32_16x16x32_bf16(a[mm], bb[nn], acc[mm][nn], 0, 0, 0);
    }
    __syncthreads();
  }

  float* Cs = (float*)smem;
#pragma unroll
  for (int mm = 0; mm < 2; ++mm)
#pragma unroll
    for (int nn = 0; nn < 2; ++nn)
#pragma unroll
      for (int r = 0; r < 4; ++r)
        Cs[(wr * 32 + mm * 16 + 4 * g + r) * 68 + wc * 32 + nn * 16 + sl] = acc[mm][nn][r];
  __syncthreads();

  const int hh2 = o0 >> 6;
  const int bh  = b * HH + hh2;
  if (m == 0) {
    // Q row-major: dst[(bh*1024 + t)*64 + d]
    const int t = tid >> 2, oq = tid & 3;
    bf16x8_t p0, p1;
#pragma unroll
    for (int i = 0; i < 8; ++i) {
      p0[i] = (__bf16)(Cs[(oq * 16 + i) * 68 + t] + bias[o0 + oq * 16 + i]);
      p1[i] = (__bf16)(Cs[(oq * 16 + 8 + i) * 68 + t] + bias[o0 + oq * 16 + 8 + i]);
    }
    bf16* dp = qw + ((size_t)bh * TT + t0 + t) * HD + oq * 16;
    *(bf16x8_t*)dp = p0;
    *(bf16x8_t*)(dp + 8) = p1;
  } else if (m == 1) {
    // K frag: tid -> (st = tid>>6, lane = tid&63); two halves
    const int st = tid >> 6;             // local st 0..3
    const int l2 = tid & 63;
    const int g2 = l2 >> 4, q2 = l2 & 15;
    bf16* dpf = kfrag + (((size_t)bh * 64 + (t0 >> 4) + st) * 2) * 512;
#pragma unroll
    for (int half = 0; half < 2; ++half) {
      bf16x8_t p;
#pragma unroll
      for (int j = 0; j < 8; ++j) {
        const int d = half * 32 + g2 * 8 + j;
        p[j] = (__bf16)(Cs[d * 68 + st * 16 + q2] + bias[o0 + d]);
      }
      *(bf16x8_t*)(dpf + half * 512 + l2 * 8) = p;
    }
  } else {
    // V frag: tid -> (dt = tid>>6, lane = tid&63); two i2 sub-tiles
    const int dt = tid >> 6;             // 0..3
    const int l2 = tid & 63;
    const int g2 = l2 >> 4, q2 = l2 & 15;
    const int d  = dt * 16 + q2;
    const float bv_ = bias[o0 + d];
#pragma unroll
    for (int i2p = 0; i2p < 2; ++i2p) {
      const int i2 = (t0 >> 5) + i2p;
      bf16x8_t p;
#pragma unroll
      for (int j = 0; j < 8; ++j) {
        const int tloc = i2p * 32 + g2 * 8 + j;
        p[j] = (__bf16)(Cs[d * 68 + tloc] + bv_);
      }
      *(bf16x8_t*)(vfrag + ((((size_t)bh * 32 + i2) * 4 + dt) * 64 + l2) * 8) = p;
    }
  }
}

__global__ __launch_bounds__(256) void gemm_out(
    const bf16* __restrict__ S, const float* __restrict__ Wp,
    const float* __restrict__ bp, float* __restrict__ out) {
  __shared__ __align__(16) char smem[2 * 64 * 72 * 2];
  __bf16* Ws = (__bf16*)smem;
  __bf16* Xs = (__bf16*)(smem + 64 * 72 * 2);

  const int o0 = blockIdx.y * 64;
  const int t0 = blockIdx.x * 64;
  const int b  = blockIdx.z;
  const int tid = threadIdx.x;
  const int w = tid >> 6, l = tid & 63, g = l >> 4, sl = l & 15;
  const int wr = w >> 1, wc = w & 1;

  f32x4_t acc[2][2] = {};
  for (int c0 = 0; c0 < CC; c0 += 64) {
    {
      const int oi = tid >> 4, c4 = (tid & 15) * 4;
#pragma unroll
      for (int op = 0; op < 4; ++op) {
        const int o = op * 16 + oi;
        const float4 w4 = *(const float4*)&Wp[(size_t)(o0 + o) * CC + c0 + c4];
        bf16x4_t p;
        p[0] = (__bf16)w4.x; p[1] = (__bf16)w4.y;
        p[2] = (__bf16)w4.z; p[3] = (__bf16)w4.w;
        *(bf16x4_t*)&Ws[o * 72 + c4] = p;
      }
    }
    {
      const int t4 = (tid & 15) * 4, ci = tid >> 4;
#pragma unroll
      for (int cp = 0; cp < 4; ++cp) {
        const int c = cp * 16 + ci;
        const bf16x4_t x4 = *(const bf16x4_t*)&S[((size_t)b * CC + c0 + c) * TT + t0 + t4];
        Xs[(t4 + 0) * 72 + c] = x4[0];
        Xs[(t4 + 1) * 72 + c] = x4[1];
        Xs[(t4 + 2) * 72 + c] = x4[2];
        Xs[(t4 + 3) * 72 + c] = x4[3];
      }
    }
    __syncthreads();
#pragma unroll
    for (int kk = 0; kk < 2; ++kk) {
      bf16x8_t a[2], bb[2];
#pragma unroll
      for (int mm = 0; mm < 2; ++mm)
        a[mm] = *(const bf16x8_t*)&Ws[(wr * 32 + mm * 16 + sl) * 72 + kk * 32 + g * 8];
#pragma unroll
      for (int nn = 0; nn < 2; ++nn)
        bb[nn] = *(const bf16x8_t*)&Xs[(wc * 32 + nn * 16 + sl) * 72 + kk * 32 + g * 8];
#pragma unroll
      for (int mm = 0; mm < 2; ++mm)
#pragma unroll
        for (int nn = 0; nn < 2; ++nn)
          acc[mm][nn] = __builtin_amdgcn_mfma_f32_16x16x32_bf16(a[mm], bb[nn], acc[mm][nn], 0, 0, 0);
    }
    __syncthreads();
  }

  float* Cs = (float*)smem;
#pragma unroll
  for (int mm = 0; mm < 2; ++mm)
#pragma unroll
    for (int nn = 0; nn < 2; ++nn)
#pragma unroll
      for (int r = 0; r < 4; ++r)
        Cs[(wr * 32 + mm * 16 + 4 * g + r) * 68 + wc * 32 + nn * 16 + sl] = acc[mm][nn][r];
  __syncthreads();

  const int o = tid >> 2, tq = tid & 3;
  const float bv_ = bp[o0 + o];
  float* dp = out + ((size_t)b * NCOUT + o0 + o) * TT + t0 + tq * 16;
#pragma unroll
  for (int i4 = 0; i4 < 4; ++i4) {
    f32x4_t v = *(const f32x4_t*)&Cs[o * 68 + tq * 16 + i4 * 4];
    v[0] += bv_; v[1] += bv_; v[2] += bv_; v[3] += bv_;
    *(f32x4_t*)(dp + i4 * 4) = v;
  }
}

// ===========================================================================
// attn v9 = v7 structure, but K/V read from pre-fragmented layouts:
// every K/V load is a contiguous 1KB wave access (8 fully-used lines).
// ===========================================================================
__global__ __launch_bounds__(256, 4) void attn_v9(
    const bf16* __restrict__ qw, const bf16* __restrict__ kfrag,
    const bf16* __restrict__ vfrag,
    const float* __restrict__ wK, const float* __restrict__ wV,
    float* __restrict__ align_out, bf16* __restrict__ attnw) {
  const int fi   = blockIdx.x;
  const int xcd  = fi & 7;
  const int k2   = fi >> 3;
  const int bh   = ((k2 >> 6) << 3) + xcd;
  const int qblk = k2 & 63;
  const int b = bh >> 3, h = bh & 7;
  const int q0 = qblk * 16;

  const int tid = threadIdx.x;
  const int w = tid >> 6, l = tid & 63, g = l >> 4, ql = l & 15;
  const int qabs  = q0 + ql;
  const int sbase = w * 256;

  // LDS: eL [64 rows][264 bf16] (33792 B) | bandv 3072 | bandP 2304 | red 256
  __shared__ __align__(16) char smem[39424];
  __bf16* eL    = (__bf16*)smem;
  float* bandv  = (float*)(smem + 33792);
  float* bandP  = (float*)(smem + 36864);
  float* redbuf = (float*)(smem + 39168);
  float* obuf   = (float*)smem;                 // overlay after barrier (17408 B)
  float* stg    = (float*)(smem + 17408);       // overlay epilogue (4352 B)

  for (int i = tid; i < 576; i += 256) bandP[i] = 0.f;

  const bf16* qb = qw + ((size_t)bh * TT + qabs) * HD + g * 8;
  const bf16x8_t qa0 = *(const bf16x8_t*)qb;
  const bf16x8_t qa1 = *(const bf16x8_t*)(qb + 32);

  // band-K: D[j][q] via mfma(A=wK rows, B=Q cols)
  {
    const int j = (ql < 9) ? ql : 0;
    const float* wkr = wK + j * HD + g * 8;
    const f32x4_t w0 = *(const f32x4_t*)wkr;
    const f32x4_t w1 = *(const f32x4_t*)(wkr + 4);
    const f32x4_t w2 = *(const f32x4_t*)(wkr + 32);
    const f32x4_t w3 = *(const f32x4_t*)(wkr + 36);
    bf16x8_t ka0, ka1;
#pragma unroll
    for (int i = 0; i < 4; ++i) {
      ka0[i] = (__bf16)w0[i]; ka0[4 + i] = (__bf16)w1[i];
      ka1[i] = (__bf16)w2[i]; ka1[4 + i] = (__bf16)w3[i];
    }
    f32x4_t bacc = {0.f, 0.f, 0.f, 0.f};
    bacc = __builtin_amdgcn_mfma_f32_16x16x32_bf16(ka0, qa0, bacc, 0, 0, 0);
    bacc = __builtin_amdgcn_mfma_f32_16x16x32_bf16(ka1, qa1, bacc, 0, 0, 0);
#pragma unroll
    for (int r = 0; r < 4; ++r)
      if (4 * g + r < 9) bandv[(w * 16 + ql) * 12 + 4 * g + r] = bacc[r];
  }

  // ---- pass 1: QK + exp; K from frag layout (contiguous 1KB loads) ----
  float ls = 0.f;
  bf16x4_t stash[16];
  const int erow = (w * 16 + ql) * 264;
  // kfrag base for this wave: st global = w*16 + st_local
  const bf16* kfb = kfrag + (((size_t)bh * 64 + w * 16) * 2) * 512 + l * 8;
#pragma unroll
  for (int st = 0; st < 16; ++st) {
    const bf16x8_t k0 = *(const bf16x8_t*)(kfb + (size_t)st * 1024);
    const bf16x8_t k1 = *(const bf16x8_t*)(kfb + (size_t)st * 1024 + 512);
    f32x4_t a = {0.f, 0.f, 0.f, 0.f};
    a = __builtin_amdgcn_mfma_f32_16x16x32_bf16(k0, qa0, a, 0, 0, 0);
    a = __builtin_amdgcn_mfma_f32_16x16x32_bf16(k1, qa1, a, 0, 0, 0);
    const int s0t = sbase + st * 16;
    const bool near = (s0t + 15 >= q0 - CLIPW) && (s0t <= q0 + 15 + CLIPW);
#pragma unroll
    for (int r = 0; r < 4; ++r) {
      float x = a[r];
      if (near) {
        const int delta = s0t + 4 * g + r - qabs;
        if ((unsigned)(delta + CLIPW) <= 2 * CLIPW)
          x += bandv[(w * 16 + ql) * 12 + delta + CLIPW];
      }
      const float e = __expf(x * 0.125f);
      stash[st][r] = (__bf16)e;
      ls += e;
    }
    *(bf16x4_t*)&eL[erow + st * 16 + 4 * g] = stash[st];
  }
  ls += __shfl_xor(ls, 16);
  ls += __shfl_xor(ls, 32);
  if (l < 16) redbuf[w * 16 + ql] = ls;
  __syncthreads();
  const float inv = 1.0f / (redbuf[ql] + redbuf[16 + ql] + redbuf[32 + ql] + redbuf[48 + ql]);

  // ---- pass 2: PV from frag layout + align stores ----
  f32x4_t oacc[4] = {};
  const bf16* vfb = vfrag + (((size_t)bh * 32 + w * 8) * 4) * 512 + l * 8;
#pragma unroll
  for (int i2 = 0; i2 < 8; ++i2) {
    const bf16x8_t pb = *(const bf16x8_t*)&eL[erow + i2 * 32 + 8 * g];
#pragma unroll
    for (int dt = 0; dt < 4; ++dt) {
      const bf16x8_t va = *(const bf16x8_t*)(vfb + ((size_t)i2 * 4 + dt) * 512);
      oacc[dt] = __builtin_amdgcn_mfma_f32_16x16x32_bf16(va, pb, oacc[dt], 0, 0, 0);
    }
#pragma unroll
    for (int h2 = 0; h2 < 2; ++h2) {
      const int st = i2 * 2 + h2;
      const int s0t = sbase + st * 16;
      const bool near = (s0t + 15 >= q0 - CLIPW) && (s0t <= q0 + 15 + CLIPW);
      f32x4_t p4;
#pragma unroll
      for (int r = 0; r < 4; ++r) {
        const float p = (float)stash[st][r] * inv;
        p4[r] = p;
        if (near) {
          const int delta = s0t + 4 * g + r - qabs;
          if ((unsigned)(delta + CLIPW) <= 2 * CLIPW)
            bandP[ql * 36 + delta + CLIPW] = p;
        }
      }
      float* gp = align_out + ((size_t)bh * TT + qabs) * TT + s0t + 4 * g;
      *(f32x4_t*)gp = p4;
    }
  }
  // scale O by inv (per-lane q is fixed = ql)
#pragma unroll
  for (int dt = 0; dt < 4; ++dt) {
    oacc[dt][0] *= inv; oacc[dt][1] *= inv;
    oacc[dt][2] *= inv; oacc[dt][3] *= inv;
  }

  // ---- all eL reads must complete block-wide before obuf overlays eL ----
  __syncthreads();

#pragma unroll
  for (int dt = 0; dt < 4; ++dt)
    *(f32x4_t*)&obuf[w * 1088 + ql * 68 + dt * 16 + 4 * g] = oacc[dt];
  __syncthreads();

  // ---- epilogue (wave 0): reduce + band-V MFMA + store attn ----
  if (w == 0) {
    f32x4_t osum[4];
#pragma unroll
    for (int dt = 0; dt < 4; ++dt) {
      const int off = ql * 68 + dt * 16 + 4 * g;
      osum[dt] = *(const f32x4_t*)&obuf[off] + *(const f32x4_t*)&obuf[1088 + off] +
                 *(const f32x4_t*)&obuf[2176 + off] + *(const f32x4_t*)&obuf[3264 + off];
    }
    const f32x4_t b0 = *(const f32x4_t*)&bandP[ql * 36 + g * 8];
    const f32x4_t b1 = *(const f32x4_t*)&bandP[ql * 36 + g * 8 + 4];
    bf16x8_t pbb;
#pragma unroll
    for (int i = 0; i < 4; ++i) {
      pbb[i] = (__bf16)b0[i];
      pbb[4 + i] = (__bf16)b1[i];
    }
#pragma unroll
    for (int dt = 0; dt < 4; ++dt) {
      bf16x8_t wa;
#pragma unroll
      for (int jj = 0; jj < 8; ++jj) {
        const int j = g * 8 + jj;
        wa[jj] = (__bf16)((j < 9) ? wV[j * HD + dt * 16 + ql] : 0.f);
      }
      osum[dt] = __builtin_amdgcn_mfma_f32_16x16x32_bf16(wa, pbb, osum[dt], 0, 0, 0);
    }
#pragma unroll
    for (int dt = 0; dt < 4; ++dt)
#pragma unroll
      for (int r = 0; r < 4; ++r)
        stg[(dt * 16 + 4 * g + r) * 17 + ql] = osum[dt][r];
    bf16x8_t o0, o1;
#pragma unroll
    for (int i = 0; i < 8; ++i) {
      o0[i] = (__bf16)stg[l * 17 + i];
      o1[i] = (__bf16)stg[l * 17 + 8 + i];
    }
    bf16* dp = attnw + ((size_t)b * CC + h * HD + l) * TT + q0;
    *(bf16x8_t*)dp = o0;
    *(bf16x8_t*)(dp + 8) = o1;
  }
}

extern "C" void kernel_launch(void* const* d_in, const int* in_sizes, int n_in,
                              void* d_out, int out_size, void* d_ws, size_t ws_size,
                              hipStream_t stream) {
  const float* X  = (const float*)d_in[0];
  const float* Wq = (const float*)d_in[1];
  const float* bq = (const float*)d_in[2];
  const float* Wk = (const float*)d_in[3];
  const float* bk = (const float*)d_in[4];
  const float* Wv = (const float*)d_in[5];
  const float* bv = (const float*)d_in[6];
  const float* Wp = (const float*)d_in[7];
  const float* bp = (const float*)d_in[8];
  const float* wK = (const float*)d_in[9];
  const float* wV = (const float*)d_in[10];

  float* out       = (float*)d_out;
  float* align_out = out + (size_t)BB * NCOUT * TT;

  const size_t SZ = (size_t)BB * HH * TT * HD;
  bf16* qw    = (bf16*)d_ws;
  bf16* kfrag = qw + SZ;
  bf16* vfrag = qw + 2 * SZ;
  bf16* attnw = qw + 3 * SZ;

  gemm_qkv<<<dim3(TT / 64, 24, BB), 256, 0, stream>>>(
      X, Wq, bq, Wk, bk, Wv, bv, qw, kfrag, vfrag);
  attn_v9<<<dim3(4096), 256, 0, stream>>>(
      qw, kfrag, vfrag, wK, wV, align_out, attnw);
  gemm_out<<<dim3(TT / 64, NCOUT / 64, BB), 256, 0, stream>>>(
      attnw, Wp, bp, out);
}

// Round 13
// 186.719 us; speedup vs baseline: 1.3325x; 1.0813x over previous
//
#include <hip/hip_runtime.h>
#include <hip/hip_bf16.h>

#define BB 8
#define CC 512
#define TT 1024
#define HH 8
#define HD 64
#define CLIPW 4
#define NCOUT 512

using bf16 = __hip_bfloat16;
typedef __bf16 bf16x8_t __attribute__((ext_vector_type(8)));
typedef __bf16 bf16x4_t __attribute__((ext_vector_type(4)));
typedef float f32x4_t __attribute__((ext_vector_type(4)));

__device__ __forceinline__ float bf2f(bf16 v) {
  return __uint_as_float(((unsigned int)*(unsigned short*)&v) << 16);
}

// ===========================================================================
// K1: fused q/k/v projection. Q -> row-major [bh][t][d].
// K -> frag layout kfrag[bh][st][half][lane][8]   (st = t/16, half = k/32)
// V -> frag layout vfrag[bh][i2][dt][lane][8]     (i2 = s/32, dt = d/16)
// so attn loads are contiguous 1KB per wave instruction.
// ===========================================================================
__global__ __launch_bounds__(256) void gemm_qkv(
    const float* __restrict__ X,
    const float* __restrict__ Wq, const float* __restrict__ bq,
    const float* __restrict__ Wk, const float* __restrict__ bk,
    const float* __restrict__ Wv, const float* __restrict__ bv,
    bf16* __restrict__ qw, bf16* __restrict__ kfrag, bf16* __restrict__ vfrag) {
  __shared__ __align__(16) char smem[2 * 64 * 72 * 2];
  __bf16* Ws = (__bf16*)smem;
  __bf16* Xs = (__bf16*)(smem + 64 * 72 * 2);

  const int y  = blockIdx.y;
  const int m  = y >> 3;
  const int o0 = (y & 7) * 64;
  const int t0 = blockIdx.x * 64;
  const int b  = blockIdx.z;
  const float* W    = (m == 0) ? Wq : (m == 1) ? Wk : Wv;
  const float* bias = (m == 0) ? bq : (m == 1) ? bk : bv;

  const int tid = threadIdx.x;
  const int w = tid >> 6, l = tid & 63, g = l >> 4, sl = l & 15;
  const int wr = w >> 1, wc = w & 1;

  f32x4_t acc[2][2] = {};
  for (int c0 = 0; c0 < CC; c0 += 64) {
    {
      const int oi = tid >> 4, c4 = (tid & 15) * 4;
#pragma unroll
      for (int op = 0; op < 4; ++op) {
        const int o = op * 16 + oi;
        const float4 w4 = *(const float4*)&W[(size_t)(o0 + o) * CC + c0 + c4];
        bf16x4_t p;
        p[0] = (__bf16)w4.x; p[1] = (__bf16)w4.y;
        p[2] = (__bf16)w4.z; p[3] = (__bf16)w4.w;
        *(bf16x4_t*)&Ws[o * 72 + c4] = p;
      }
    }
    {
      const int t4 = (tid & 15) * 4, ci = tid >> 4;
#pragma unroll
      for (int cp = 0; cp < 4; ++cp) {
        const int c = cp * 16 + ci;
        const float4 x4 = *(const float4*)&X[((size_t)b * CC + c0 + c) * TT + t0 + t4];
        Xs[(t4 + 0) * 72 + c] = (__bf16)x4.x;
        Xs[(t4 + 1) * 72 + c] = (__bf16)x4.y;
        Xs[(t4 + 2) * 72 + c] = (__bf16)x4.z;
        Xs[(t4 + 3) * 72 + c] = (__bf16)x4.w;
      }
    }
    __syncthreads();
#pragma unroll
    for (int kk = 0; kk < 2; ++kk) {
      bf16x8_t a[2], bb[2];
#pragma unroll
      for (int mm = 0; mm < 2; ++mm)
        a[mm] = *(const bf16x8_t*)&Ws[(wr * 32 + mm * 16 + sl) * 72 + kk * 32 + g * 8];
#pragma unroll
      for (int nn = 0; nn < 2; ++nn)
        bb[nn] = *(const bf16x8_t*)&Xs[(wc * 32 + nn * 16 + sl) * 72 + kk * 32 + g * 8];
#pragma unroll
      for (int mm = 0; mm < 2; ++mm)
#pragma unroll
        for (int nn = 0; nn < 2; ++nn)
          acc[mm][nn] = __builtin_amdgcn_mfma_f32_16x16x32_bf16(a[mm], bb[nn], acc[mm][nn], 0, 0, 0);
    }
    __syncthreads();
  }

  float* Cs = (float*)smem;
#pragma unroll
  for (int mm = 0; mm < 2; ++mm)
#pragma unroll
    for (int nn = 0; nn < 2; ++nn)
#pragma unroll
      for (int r = 0; r < 4; ++r)
        Cs[(wr * 32 + mm * 16 + 4 * g + r) * 68 + wc * 32 + nn * 16 + sl] = acc[mm][nn][r];
  __syncthreads();

  const int hh2 = o0 >> 6;
  const int bh  = b * HH + hh2;
  if (m == 0) {
    const int t = tid >> 2, oq = tid & 3;
    bf16x8_t p0, p1;
#pragma unroll
    for (int i = 0; i < 8; ++i) {
      p0[i] = (__bf16)(Cs[(oq * 16 + i) * 68 + t] + bias[o0 + oq * 16 + i]);
      p1[i] = (__bf16)(Cs[(oq * 16 + 8 + i) * 68 + t] + bias[o0 + oq * 16 + 8 + i]);
    }
    bf16* dp = qw + ((size_t)bh * TT + t0 + t) * HD + oq * 16;
    *(bf16x8_t*)dp = p0;
    *(bf16x8_t*)(dp + 8) = p1;
  } else if (m == 1) {
    const int st = tid >> 6;             // local st 0..3
    const int l2 = tid & 63;
    const int g2 = l2 >> 4, q2 = l2 & 15;
    bf16* dpf = kfrag + (((size_t)bh * 64 + (t0 >> 4) + st) * 2) * 512;
#pragma unroll
    for (int half = 0; half < 2; ++half) {
      bf16x8_t p;
#pragma unroll
      for (int j = 0; j < 8; ++j) {
        const int d = half * 32 + g2 * 8 + j;
        p[j] = (__bf16)(Cs[d * 68 + st * 16 + q2] + bias[o0 + d]);
      }
      *(bf16x8_t*)(dpf + half * 512 + l2 * 8) = p;
    }
  } else {
    const int dt = tid >> 6;             // 0..3
    const int l2 = tid & 63;
    const int g2 = l2 >> 4, q2 = l2 & 15;
    const int d  = dt * 16 + q2;
    const float bv_ = bias[o0 + d];
#pragma unroll
    for (int i2p = 0; i2p < 2; ++i2p) {
      const int i2 = (t0 >> 5) + i2p;
      bf16x8_t p;
#pragma unroll
      for (int j = 0; j < 8; ++j) {
        const int tloc = i2p * 32 + g2 * 8 + j;
        p[j] = (__bf16)(Cs[d * 68 + tloc] + bv_);
      }
      *(bf16x8_t*)(vfrag + ((((size_t)bh * 32 + i2) * 4 + dt) * 64 + l2) * 8) = p;
    }
  }
}

__global__ __launch_bounds__(256) void gemm_out(
    const bf16* __restrict__ S, const float* __restrict__ Wp,
    const float* __restrict__ bp, float* __restrict__ out) {
  __shared__ __align__(16) char smem[2 * 64 * 72 * 2];
  __bf16* Ws = (__bf16*)smem;
  __bf16* Xs = (__bf16*)(smem + 64 * 72 * 2);

  const int o0 = blockIdx.y * 64;
  const int t0 = blockIdx.x * 64;
  const int b  = blockIdx.z;
  const int tid = threadIdx.x;
  const int w = tid >> 6, l = tid & 63, g = l >> 4, sl = l & 15;
  const int wr = w >> 1, wc = w & 1;

  f32x4_t acc[2][2] = {};
  for (int c0 = 0; c0 < CC; c0 += 64) {
    {
      const int oi = tid >> 4, c4 = (tid & 15) * 4;
#pragma unroll
      for (int op = 0; op < 4; ++op) {
        const int o = op * 16 + oi;
        const float4 w4 = *(const float4*)&Wp[(size_t)(o0 + o) * CC + c0 + c4];
        bf16x4_t p;
        p[0] = (__bf16)w4.x; p[1] = (__bf16)w4.y;
        p[2] = (__bf16)w4.z; p[3] = (__bf16)w4.w;
        *(bf16x4_t*)&Ws[o * 72 + c4] = p;
      }
    }
    {
      const int t4 = (tid & 15) * 4, ci = tid >> 4;
#pragma unroll
      for (int cp = 0; cp < 4; ++cp) {
        const int c = cp * 16 + ci;
        const bf16x4_t x4 = *(const bf16x4_t*)&S[((size_t)b * CC + c0 + c) * TT + t0 + t4];
        Xs[(t4 + 0) * 72 + c] = x4[0];
        Xs[(t4 + 1) * 72 + c] = x4[1];
        Xs[(t4 + 2) * 72 + c] = x4[2];
        Xs[(t4 + 3) * 72 + c] = x4[3];
      }
    }
    __syncthreads();
#pragma unroll
    for (int kk = 0; kk < 2; ++kk) {
      bf16x8_t a[2], bb[2];
#pragma unroll
      for (int mm = 0; mm < 2; ++mm)
        a[mm] = *(const bf16x8_t*)&Ws[(wr * 32 + mm * 16 + sl) * 72 + kk * 32 + g * 8];
#pragma unroll
      for (int nn = 0; nn < 2; ++nn)
        bb[nn] = *(const bf16x8_t*)&Xs[(wc * 32 + nn * 16 + sl) * 72 + kk * 32 + g * 8];
#pragma unroll
      for (int mm = 0; mm < 2; ++mm)
#pragma unroll
        for (int nn = 0; nn < 2; ++nn)
          acc[mm][nn] = __builtin_amdgcn_mfma_f32_16x16x32_bf16(a[mm], bb[nn], acc[mm][nn], 0, 0, 0);
    }
    __syncthreads();
  }

  float* Cs = (float*)smem;
#pragma unroll
  for (int mm = 0; mm < 2; ++mm)
#pragma unroll
    for (int nn = 0; nn < 2; ++nn)
#pragma unroll
      for (int r = 0; r < 4; ++r)
        Cs[(wr * 32 + mm * 16 + 4 * g + r) * 68 + wc * 32 + nn * 16 + sl] = acc[mm][nn][r];
  __syncthreads();

  const int o = tid >> 2, tq = tid & 3;
  const float bv_ = bp[o0 + o];
  float* dp = out + ((size_t)b * NCOUT + o0 + o) * TT + t0 + tq * 16;
#pragma unroll
  for (int i4 = 0; i4 < 4; ++i4) {
    f32x4_t v = *(const f32x4_t*)&Cs[o * 68 + tq * 16 + i4 * 4];
    v[0] += bv_; v[1] += bv_; v[2] += bv_; v[3] += bv_;
    *(f32x4_t*)(dp + i4 * 4) = v;
  }
}

// ===========================================================================
// attn v10 = v9 + dense alignment stores: per q-row, read the contiguous eL
// row (8B/lane) and emit one 1KB full-line NT store. PV loop becomes pure
// MFMA+loads. bandP extraction is a small predicated loop from stash.
// ===========================================================================
__global__ __launch_bounds__(256, 4) void attn_v10(
    const bf16* __restrict__ qw, const bf16* __restrict__ kfrag,
    const bf16* __restrict__ vfrag,
    const float* __restrict__ wK, const float* __restrict__ wV,
    float* __restrict__ align_out, bf16* __restrict__ attnw) {
  const int fi   = blockIdx.x;
  const int xcd  = fi & 7;
  const int k2   = fi >> 3;
  const int bh   = ((k2 >> 6) << 3) + xcd;
  const int qblk = k2 & 63;
  const int b = bh >> 3, h = bh & 7;
  const int q0 = qblk * 16;

  const int tid = threadIdx.x;
  const int w = tid >> 6, l = tid & 63, g = l >> 4, ql = l & 15;
  const int qabs  = q0 + ql;
  const int sbase = w * 256;

  // LDS: eL [64 rows][264 bf16] (33792 B) | bandv 3072 | bandP 2304 | red 256
  __shared__ __align__(16) char smem[39424];
  __bf16* eL    = (__bf16*)smem;
  float* bandv  = (float*)(smem + 33792);
  float* bandP  = (float*)(smem + 36864);
  float* redbuf = (float*)(smem + 39168);
  float* invL   = (float*)(smem + 33792);       // overlays bandv (free after p1)
  float* obuf   = (float*)smem;                 // overlay after barrier (17408 B)
  float* stg    = (float*)(smem + 17408);       // overlay epilogue (4352 B)

  for (int i = tid; i < 576; i += 256) bandP[i] = 0.f;

  const bf16* qb = qw + ((size_t)bh * TT + qabs) * HD + g * 8;
  const bf16x8_t qa0 = *(const bf16x8_t*)qb;
  const bf16x8_t qa1 = *(const bf16x8_t*)(qb + 32);

  // band-K: D[j][q] via mfma(A=wK rows, B=Q cols)
  {
    const int j = (ql < 9) ? ql : 0;
    const float* wkr = wK + j * HD + g * 8;
    const f32x4_t w0 = *(const f32x4_t*)wkr;
    const f32x4_t w1 = *(const f32x4_t*)(wkr + 4);
    const f32x4_t w2 = *(const f32x4_t*)(wkr + 32);
    const f32x4_t w3 = *(const f32x4_t*)(wkr + 36);
    bf16x8_t ka0, ka1;
#pragma unroll
    for (int i = 0; i < 4; ++i) {
      ka0[i] = (__bf16)w0[i]; ka0[4 + i] = (__bf16)w1[i];
      ka1[i] = (__bf16)w2[i]; ka1[4 + i] = (__bf16)w3[i];
    }
    f32x4_t bacc = {0.f, 0.f, 0.f, 0.f};
    bacc = __builtin_amdgcn_mfma_f32_16x16x32_bf16(ka0, qa0, bacc, 0, 0, 0);
    bacc = __builtin_amdgcn_mfma_f32_16x16x32_bf16(ka1, qa1, bacc, 0, 0, 0);
#pragma unroll
    for (int r = 0; r < 4; ++r)
      if (4 * g + r < 9) bandv[(w * 16 + ql) * 12 + 4 * g + r] = bacc[r];
  }

  // ---- pass 1: QK + exp; K from frag layout; stash regs + k-major eL ----
  float ls = 0.f;
  bf16x4_t stash[16];
  const int erow = (w * 16 + ql) * 264;
  const bf16* kfb = kfrag + (((size_t)bh * 64 + w * 16) * 2) * 512 + l * 8;
#pragma unroll
  for (int st = 0; st < 16; ++st) {
    const bf16x8_t k0 = *(const bf16x8_t*)(kfb + (size_t)st * 1024);
    const bf16x8_t k1 = *(const bf16x8_t*)(kfb + (size_t)st * 1024 + 512);
    f32x4_t a = {0.f, 0.f, 0.f, 0.f};
    a = __builtin_amdgcn_mfma_f32_16x16x32_bf16(k0, qa0, a, 0, 0, 0);
    a = __builtin_amdgcn_mfma_f32_16x16x32_bf16(k1, qa1, a, 0, 0, 0);
    const int s0t = sbase + st * 16;
    const bool near = (s0t + 15 >= q0 - CLIPW) && (s0t <= q0 + 15 + CLIPW);
#pragma unroll
    for (int r = 0; r < 4; ++r) {
      float x = a[r];
      if (near) {
        const int delta = s0t + 4 * g + r - qabs;
        if ((unsigned)(delta + CLIPW) <= 2 * CLIPW)
          x += bandv[(w * 16 + ql) * 12 + delta + CLIPW];
      }
      const float e = __expf(x * 0.125f);
      stash[st][r] = (__bf16)e;
      ls += e;
    }
    *(bf16x4_t*)&eL[erow + st * 16 + 4 * g] = stash[st];
  }
  ls += __shfl_xor(ls, 16);
  ls += __shfl_xor(ls, 32);
  if (l < 16) redbuf[w * 16 + ql] = ls;
  __syncthreads();
  const float inv = 1.0f / (redbuf[ql] + redbuf[16 + ql] + redbuf[32 + ql] + redbuf[48 + ql]);
  if (l < 16) invL[w * 16 + l] = inv;   // inv for q-row l (ql==l here)

  // ---- dense alignment stores: one full q-row (1KB, 8 full lines) per iter
  {
    float* abase = align_out + ((size_t)bh * TT + q0) * TT + sbase + l * 4;
#pragma unroll
    for (int q = 0; q < 16; ++q) {
      const float iq = invL[w * 16 + q];
      const bf16x4_t e4 = *(const bf16x4_t*)&eL[(w * 16 + q) * 264 + l * 4];
      f32x4_t p4;
      p4[0] = (float)e4[0] * iq;
      p4[1] = (float)e4[1] * iq;
      p4[2] = (float)e4[2] * iq;
      p4[3] = (float)e4[3] * iq;
      __builtin_nontemporal_store(p4, (f32x4_t*)(abase + (size_t)q * TT));
    }
  }

  // ---- bandP extraction (predicated, mostly skipped) ----
#pragma unroll
  for (int st = 0; st < 16; ++st) {
    const int s0t = sbase + st * 16;
    const bool near = (s0t + 15 >= q0 - CLIPW) && (s0t <= q0 + 15 + CLIPW);
    if (near) {
#pragma unroll
      for (int r = 0; r < 4; ++r) {
        const int delta = s0t + 4 * g + r - qabs;
        if ((unsigned)(delta + CLIPW) <= 2 * CLIPW)
          bandP[ql * 36 + delta + CLIPW] = (float)stash[st][r] * inv;
      }
    }
  }

  // ---- pass 2: pure PV from frag layout ----
  f32x4_t oacc[4] = {};
  const bf16* vfb = vfrag + (((size_t)bh * 32 + w * 8) * 4) * 512 + l * 8;
#pragma unroll
  for (int i2 = 0; i2 < 8; ++i2) {
    const bf16x8_t pb = *(const bf16x8_t*)&eL[erow + i2 * 32 + 8 * g];
#pragma unroll
    for (int dt = 0; dt < 4; ++dt) {
      const bf16x8_t va = *(const bf16x8_t*)(vfb + ((size_t)i2 * 4 + dt) * 512);
      oacc[dt] = __builtin_amdgcn_mfma_f32_16x16x32_bf16(va, pb, oacc[dt], 0, 0, 0);
    }
  }
#pragma unroll
  for (int dt = 0; dt < 4; ++dt) {
    oacc[dt][0] *= inv; oacc[dt][1] *= inv;
    oacc[dt][2] *= inv; oacc[dt][3] *= inv;
  }

  // ---- all eL reads must complete block-wide before obuf overlays eL ----
  __syncthreads();

#pragma unroll
  for (int dt = 0; dt < 4; ++dt)
    *(f32x4_t*)&obuf[w * 1088 + ql * 68 + dt * 16 + 4 * g] = oacc[dt];
  __syncthreads();

  // ---- epilogue (wave 0): reduce + band-V MFMA + store attn ----
  if (w == 0) {
    f32x4_t osum[4];
#pragma unroll
    for (int dt = 0; dt < 4; ++dt) {
      const int off = ql * 68 + dt * 16 + 4 * g;
      osum[dt] = *(const f32x4_t*)&obuf[off] + *(const f32x4_t*)&obuf[1088 + off] +
                 *(const f32x4_t*)&obuf[2176 + off] + *(const f32x4_t*)&obuf[3264 + off];
    }
    const f32x4_t b0 = *(const f32x4_t*)&bandP[ql * 36 + g * 8];
    const f32x4_t b1 = *(const f32x4_t*)&bandP[ql * 36 + g * 8 + 4];
    bf16x8_t pbb;
#pragma unroll
    for (int i = 0; i < 4; ++i) {
      pbb[i] = (__bf16)b0[i];
      pbb[4 + i] = (__bf16)b1[i];
    }
#pragma unroll
    for (int dt = 0; dt < 4; ++dt) {
      bf16x8_t wa;
#pragma unroll
      for (int jj = 0; jj < 8; ++jj) {
        const int j = g * 8 + jj;
        wa[jj] = (__bf16)((j < 9) ? wV[j * HD + dt * 16 + ql] : 0.f);
      }
      osum[dt] = __builtin_amdgcn_mfma_f32_16x16x32_bf16(wa, pbb, osum[dt], 0, 0, 0);
    }
#pragma unroll
    for (int dt = 0; dt < 4; ++dt)
#pragma unroll
      for (int r = 0; r < 4; ++r)
        stg[(dt * 16 + 4 * g + r) * 17 + ql] = osum[dt][r];
    bf16x8_t o0, o1;
#pragma unroll
    for (int i = 0; i < 8; ++i) {
      o0[i] = (__bf16)stg[l * 17 + i];
      o1[i] = (__bf16)stg[l * 17 + 8 + i];
    }
    bf16* dp = attnw + ((size_t)b * CC + h * HD + l) * TT + q0;
    *(bf16x8_t*)dp = o0;
    *(bf16x8_t*)(dp + 8) = o1;
  }
}

extern "C" void kernel_launch(void* const* d_in, const int* in_sizes, int n_in,
                              void* d_out, int out_size, void* d_ws, size_t ws_size,
                              hipStream_t stream) {
  const float* X  = (const float*)d_in[0];
  const float* Wq = (const float*)d_in[1];
  const float* bq = (const float*)d_in[2];
  const float* Wk = (const float*)d_in[3];
  const float* bk = (const float*)d_in[4];
  const float* Wv = (const float*)d_in[5];
  const float* bv = (const float*)d_in[6];
  const float* Wp = (const float*)d_in[7];
  const float* bp = (const float*)d_in[8];
  const float* wK = (const float*)d_in[9];
  const float* wV = (const float*)d_in[10];

  float* out       = (float*)d_out;
  float* align_out = out + (size_t)BB * NCOUT * TT;

  const size_t SZ = (size_t)BB * HH * TT * HD;
  bf16* qw    = (bf16*)d_ws;
  bf16* kfrag = qw + SZ;
  bf16* vfrag = qw + 2 * SZ;
  bf16* attnw = qw + 3 * SZ;

  gemm_qkv<<<dim3(TT / 64, 24, BB), 256, 0, stream>>>(
      X, Wq, bq, Wk, bk, Wv, bv, qw, kfrag, vfrag);
  attn_v10<<<dim3(4096), 256, 0, stream>>>(
      qw, kfrag, vfrag, wK, wV, align_out, attnw);
  gemm_out<<<dim3(TT / 64, NCOUT / 64, BB), 256, 0, stream>>>(
      attnw, Wp, bp, out);
}

// Round 14
// 183.796 us; speedup vs baseline: 1.3537x; 1.0159x over previous
//
#include <hip/hip_runtime.h>
#include <hip/hip_bf16.h>

#define BB 8
#define CC 512
#define TT 1024
#define HH 8
#define HD 64
#define CLIPW 4
#define NCOUT 512

using bf16 = __hip_bfloat16;
typedef __bf16 bf16x8_t __attribute__((ext_vector_type(8)));
typedef __bf16 bf16x4_t __attribute__((ext_vector_type(4)));
typedef float f32x4_t __attribute__((ext_vector_type(4)));

__device__ __forceinline__ float bf2f(bf16 v) {
  return __uint_as_float(((unsigned int)*(unsigned short*)&v) << 16);
}

// ===========================================================================
// K1: fused q/k/v projection. Q -> row-major [bh][t][d].
// K -> frag layout kfrag[bh][st][half][lane][8]   (st = t/16, half = k/32)
// V -> frag layout vfrag[bh][i2][dt][lane][8]     (i2 = s/32, dt = d/16)
// ===========================================================================
__global__ __launch_bounds__(256) void gemm_qkv(
    const float* __restrict__ X,
    const float* __restrict__ Wq, const float* __restrict__ bq,
    const float* __restrict__ Wk, const float* __restrict__ bk,
    const float* __restrict__ Wv, const float* __restrict__ bv,
    bf16* __restrict__ qw, bf16* __restrict__ kfrag, bf16* __restrict__ vfrag) {
  __shared__ __align__(16) char smem[2 * 64 * 72 * 2];
  __bf16* Ws = (__bf16*)smem;
  __bf16* Xs = (__bf16*)(smem + 64 * 72 * 2);

  const int y  = blockIdx.y;
  const int m  = y >> 3;
  const int o0 = (y & 7) * 64;
  const int t0 = blockIdx.x * 64;
  const int b  = blockIdx.z;
  const float* W    = (m == 0) ? Wq : (m == 1) ? Wk : Wv;
  const float* bias = (m == 0) ? bq : (m == 1) ? bk : bv;

  const int tid = threadIdx.x;
  const int w = tid >> 6, l = tid & 63, g = l >> 4, sl = l & 15;
  const int wr = w >> 1, wc = w & 1;

  f32x4_t acc[2][2] = {};
  for (int c0 = 0; c0 < CC; c0 += 64) {
    {
      const int oi = tid >> 4, c4 = (tid & 15) * 4;
#pragma unroll
      for (int op = 0; op < 4; ++op) {
        const int o = op * 16 + oi;
        const float4 w4 = *(const float4*)&W[(size_t)(o0 + o) * CC + c0 + c4];
        bf16x4_t p;
        p[0] = (__bf16)w4.x; p[1] = (__bf16)w4.y;
        p[2] = (__bf16)w4.z; p[3] = (__bf16)w4.w;
        *(bf16x4_t*)&Ws[o * 72 + c4] = p;
      }
    }
    {
      const int t4 = (tid & 15) * 4, ci = tid >> 4;
#pragma unroll
      for (int cp = 0; cp < 4; ++cp) {
        const int c = cp * 16 + ci;
        const float4 x4 = *(const float4*)&X[((size_t)b * CC + c0 + c) * TT + t0 + t4];
        Xs[(t4 + 0) * 72 + c] = (__bf16)x4.x;
        Xs[(t4 + 1) * 72 + c] = (__bf16)x4.y;
        Xs[(t4 + 2) * 72 + c] = (__bf16)x4.z;
        Xs[(t4 + 3) * 72 + c] = (__bf16)x4.w;
      }
    }
    __syncthreads();
#pragma unroll
    for (int kk = 0; kk < 2; ++kk) {
      bf16x8_t a[2], bb[2];
#pragma unroll
      for (int mm = 0; mm < 2; ++mm)
        a[mm] = *(const bf16x8_t*)&Ws[(wr * 32 + mm * 16 + sl) * 72 + kk * 32 + g * 8];
#pragma unroll
      for (int nn = 0; nn < 2; ++nn)
        bb[nn] = *(const bf16x8_t*)&Xs[(wc * 32 + nn * 16 + sl) * 72 + kk * 32 + g * 8];
#pragma unroll
      for (int mm = 0; mm < 2; ++mm)
#pragma unroll
        for (int nn = 0; nn < 2; ++nn)
          acc[mm][nn] = __builtin_amdgcn_mfma_f32_16x16x32_bf16(a[mm], bb[nn], acc[mm][nn], 0, 0, 0);
    }
    __syncthreads();
  }

  float* Cs = (float*)smem;
#pragma unroll
  for (int mm = 0; mm < 2; ++mm)
#pragma unroll
    for (int nn = 0; nn < 2; ++nn)
#pragma unroll
      for (int r = 0; r < 4; ++r)
        Cs[(wr * 32 + mm * 16 + 4 * g + r) * 68 + wc * 32 + nn * 16 + sl] = acc[mm][nn][r];
  __syncthreads();

  const int hh2 = o0 >> 6;
  const int bh  = b * HH + hh2;
  if (m == 0) {
    const int t = tid >> 2, oq = tid & 3;
    bf16x8_t p0, p1;
#pragma unroll
    for (int i = 0; i < 8; ++i) {
      p0[i] = (__bf16)(Cs[(oq * 16 + i) * 68 + t] + bias[o0 + oq * 16 + i]);
      p1[i] = (__bf16)(Cs[(oq * 16 + 8 + i) * 68 + t] + bias[o0 + oq * 16 + 8 + i]);
    }
    bf16* dp = qw + ((size_t)bh * TT + t0 + t) * HD + oq * 16;
    *(bf16x8_t*)dp = p0;
    *(bf16x8_t*)(dp + 8) = p1;
  } else if (m == 1) {
    const int st = tid >> 6;             // local st 0..3
    const int l2 = tid & 63;
    const int g2 = l2 >> 4, q2 = l2 & 15;
    bf16* dpf = kfrag + (((size_t)bh * 64 + (t0 >> 4) + st) * 2) * 512;
#pragma unroll
    for (int half = 0; half < 2; ++half) {
      bf16x8_t p;
#pragma unroll
      for (int j = 0; j < 8; ++j) {
        const int d = half * 32 + g2 * 8 + j;
        p[j] = (__bf16)(Cs[d * 68 + st * 16 + q2] + bias[o0 + d]);
      }
      *(bf16x8_t*)(dpf + half * 512 + l2 * 8) = p;
    }
  } else {
    const int dt = tid >> 6;             // 0..3
    const int l2 = tid & 63;
    const int g2 = l2 >> 4, q2 = l2 & 15;
    const int d  = dt * 16 + q2;
    const float bv_ = bias[o0 + d];
#pragma unroll
    for (int i2p = 0; i2p < 2; ++i2p) {
      const int i2 = (t0 >> 5) + i2p;
      bf16x8_t p;
#pragma unroll
      for (int j = 0; j < 8; ++j) {
        const int tloc = i2p * 32 + g2 * 8 + j;
        p[j] = (__bf16)(Cs[d * 68 + tloc] + bv_);
      }
      *(bf16x8_t*)(vfrag + ((((size_t)bh * 32 + i2) * 4 + dt) * 64 + l2) * 8) = p;
    }
  }
}

__global__ __launch_bounds__(256) void gemm_out(
    const bf16* __restrict__ S, const float* __restrict__ Wp,
    const float* __restrict__ bp, float* __restrict__ out) {
  __shared__ __align__(16) char smem[2 * 64 * 72 * 2];
  __bf16* Ws = (__bf16*)smem;
  __bf16* Xs = (__bf16*)(smem + 64 * 72 * 2);

  const int o0 = blockIdx.y * 64;
  const int t0 = blockIdx.x * 64;
  const int b  = blockIdx.z;
  const int tid = threadIdx.x;
  const int w = tid >> 6, l = tid & 63, g = l >> 4, sl = l & 15;
  const int wr = w >> 1, wc = w & 1;

  f32x4_t acc[2][2] = {};
  for (int c0 = 0; c0 < CC; c0 += 64) {
    {
      const int oi = tid >> 4, c4 = (tid & 15) * 4;
#pragma unroll
      for (int op = 0; op < 4; ++op) {
        const int o = op * 16 + oi;
        const float4 w4 = *(const float4*)&Wp[(size_t)(o0 + o) * CC + c0 + c4];
        bf16x4_t p;
        p[0] = (__bf16)w4.x; p[1] = (__bf16)w4.y;
        p[2] = (__bf16)w4.z; p[3] = (__bf16)w4.w;
        *(bf16x4_t*)&Ws[o * 72 + c4] = p;
      }
    }
    {
      const int t4 = (tid & 15) * 4, ci = tid >> 4;
#pragma unroll
      for (int cp = 0; cp < 4; ++cp) {
        const int c = cp * 16 + ci;
        const bf16x4_t x4 = *(const bf16x4_t*)&S[((size_t)b * CC + c0 + c) * TT + t0 + t4];
        Xs[(t4 + 0) * 72 + c] = x4[0];
        Xs[(t4 + 1) * 72 + c] = x4[1];
        Xs[(t4 + 2) * 72 + c] = x4[2];
        Xs[(t4 + 3) * 72 + c] = x4[3];
      }
    }
    __syncthreads();
#pragma unroll
    for (int kk = 0; kk < 2; ++kk) {
      bf16x8_t a[2], bb[2];
#pragma unroll
      for (int mm = 0; mm < 2; ++mm)
        a[mm] = *(const bf16x8_t*)&Ws[(wr * 32 + mm * 16 + sl) * 72 + kk * 32 + g * 8];
#pragma unroll
      for (int nn = 0; nn < 2; ++nn)
        bb[nn] = *(const bf16x8_t*)&Xs[(wc * 32 + nn * 16 + sl) * 72 + kk * 32 + g * 8];
#pragma unroll
      for (int mm = 0; mm < 2; ++mm)
#pragma unroll
        for (int nn = 0; nn < 2; ++nn)
          acc[mm][nn] = __builtin_amdgcn_mfma_f32_16x16x32_bf16(a[mm], bb[nn], acc[mm][nn], 0, 0, 0);
    }
    __syncthreads();
  }

  float* Cs = (float*)smem;
#pragma unroll
  for (int mm = 0; mm < 2; ++mm)
#pragma unroll
    for (int nn = 0; nn < 2; ++nn)
#pragma unroll
      for (int r = 0; r < 4; ++r)
        Cs[(wr * 32 + mm * 16 + 4 * g + r) * 68 + wc * 32 + nn * 16 + sl] = acc[mm][nn][r];
  __syncthreads();

  const int o = tid >> 2, tq = tid & 3;
  const float bv_ = bp[o0 + o];
  float* dp = out + ((size_t)b * NCOUT + o0 + o) * TT + t0 + tq * 16;
#pragma unroll
  for (int i4 = 0; i4 < 4; ++i4) {
    f32x4_t v = *(const f32x4_t*)&Cs[o * 68 + tq * 16 + i4 * 4];
    v[0] += bv_; v[1] += bv_; v[2] += bv_; v[3] += bv_;
    *(f32x4_t*)(dp + i4 * 4) = v;
  }
}

// ===========================================================================
// attn v11 = v10 with the dense alignment stores interleaved into the PV
// loop (2 q-rows per i2 iteration) to smooth the HBM write burst.
// ===========================================================================
__global__ __launch_bounds__(256, 4) void attn_v11(
    const bf16* __restrict__ qw, const bf16* __restrict__ kfrag,
    const bf16* __restrict__ vfrag,
    const float* __restrict__ wK, const float* __restrict__ wV,
    float* __restrict__ align_out, bf16* __restrict__ attnw) {
  const int fi   = blockIdx.x;
  const int xcd  = fi & 7;
  const int k2   = fi >> 3;
  const int bh   = ((k2 >> 6) << 3) + xcd;
  const int qblk = k2 & 63;
  const int b = bh >> 3, h = bh & 7;
  const int q0 = qblk * 16;

  const int tid = threadIdx.x;
  const int w = tid >> 6, l = tid & 63, g = l >> 4, ql = l & 15;
  const int qabs  = q0 + ql;
  const int sbase = w * 256;

  // LDS: eL [64 rows][264 bf16] (33792 B) | bandv 3072 | bandP 2304 | red 256
  __shared__ __align__(16) char smem[39424];
  __bf16* eL    = (__bf16*)smem;
  float* bandv  = (float*)(smem + 33792);
  float* bandP  = (float*)(smem + 36864);
  float* redbuf = (float*)(smem + 39168);
  float* invL   = (float*)(smem + 33792);       // overlays bandv (free after p1)
  float* obuf   = (float*)smem;                 // overlay after barrier (17408 B)
  float* stg    = (float*)(smem + 17408);       // overlay epilogue (4352 B)

  for (int i = tid; i < 576; i += 256) bandP[i] = 0.f;

  const bf16* qb = qw + ((size_t)bh * TT + qabs) * HD + g * 8;
  const bf16x8_t qa0 = *(const bf16x8_t*)qb;
  const bf16x8_t qa1 = *(const bf16x8_t*)(qb + 32);

  // band-K: D[j][q] via mfma(A=wK rows, B=Q cols)
  {
    const int j = (ql < 9) ? ql : 0;
    const float* wkr = wK + j * HD + g * 8;
    const f32x4_t w0 = *(const f32x4_t*)wkr;
    const f32x4_t w1 = *(const f32x4_t*)(wkr + 4);
    const f32x4_t w2 = *(const f32x4_t*)(wkr + 32);
    const f32x4_t w3 = *(const f32x4_t*)(wkr + 36);
    bf16x8_t ka0, ka1;
#pragma unroll
    for (int i = 0; i < 4; ++i) {
      ka0[i] = (__bf16)w0[i]; ka0[4 + i] = (__bf16)w1[i];
      ka1[i] = (__bf16)w2[i]; ka1[4 + i] = (__bf16)w3[i];
    }
    f32x4_t bacc = {0.f, 0.f, 0.f, 0.f};
    bacc = __builtin_amdgcn_mfma_f32_16x16x32_bf16(ka0, qa0, bacc, 0, 0, 0);
    bacc = __builtin_amdgcn_mfma_f32_16x16x32_bf16(ka1, qa1, bacc, 0, 0, 0);
#pragma unroll
    for (int r = 0; r < 4; ++r)
      if (4 * g + r < 9) bandv[(w * 16 + ql) * 12 + 4 * g + r] = bacc[r];
  }

  // ---- pass 1: QK + exp; K from frag layout; stash regs + k-major eL ----
  float ls = 0.f;
  bf16x4_t stash[16];
  const int erow = (w * 16 + ql) * 264;
  const bf16* kfb = kfrag + (((size_t)bh * 64 + w * 16) * 2) * 512 + l * 8;
#pragma unroll
  for (int st = 0; st < 16; ++st) {
    const bf16x8_t k0 = *(const bf16x8_t*)(kfb + (size_t)st * 1024);
    const bf16x8_t k1 = *(const bf16x8_t*)(kfb + (size_t)st * 1024 + 512);
    f32x4_t a = {0.f, 0.f, 0.f, 0.f};
    a = __builtin_amdgcn_mfma_f32_16x16x32_bf16(k0, qa0, a, 0, 0, 0);
    a = __builtin_amdgcn_mfma_f32_16x16x32_bf16(k1, qa1, a, 0, 0, 0);
    const int s0t = sbase + st * 16;
    const bool near = (s0t + 15 >= q0 - CLIPW) && (s0t <= q0 + 15 + CLIPW);
#pragma unroll
    for (int r = 0; r < 4; ++r) {
      float x = a[r];
      if (near) {
        const int delta = s0t + 4 * g + r - qabs;
        if ((unsigned)(delta + CLIPW) <= 2 * CLIPW)
          x += bandv[(w * 16 + ql) * 12 + delta + CLIPW];
      }
      const float e = __expf(x * 0.125f);
      stash[st][r] = (__bf16)e;
      ls += e;
    }
    *(bf16x4_t*)&eL[erow + st * 16 + 4 * g] = stash[st];
  }
  ls += __shfl_xor(ls, 16);
  ls += __shfl_xor(ls, 32);
  if (l < 16) redbuf[w * 16 + ql] = ls;
  __syncthreads();
  const float inv = 1.0f / (redbuf[ql] + redbuf[16 + ql] + redbuf[32 + ql] + redbuf[48 + ql]);
  if (l < 16) invL[w * 16 + l] = inv;   // inv for q-row l

  // ---- bandP extraction (predicated, mostly skipped) ----
#pragma unroll
  for (int st = 0; st < 16; ++st) {
    const int s0t = sbase + st * 16;
    const bool near = (s0t + 15 >= q0 - CLIPW) && (s0t <= q0 + 15 + CLIPW);
    if (near) {
#pragma unroll
      for (int r = 0; r < 4; ++r) {
        const int delta = s0t + 4 * g + r - qabs;
        if ((unsigned)(delta + CLIPW) <= 2 * CLIPW)
          bandP[ql * 36 + delta + CLIPW] = (float)stash[st][r] * inv;
      }
    }
  }

  // ---- pass 2: PV + interleaved dense align stores (2 q-rows / iter) ----
  f32x4_t oacc[4] = {};
  const bf16* vfb = vfrag + (((size_t)bh * 32 + w * 8) * 4) * 512 + l * 8;
  float* abase = align_out + ((size_t)bh * TT + q0) * TT + sbase + l * 4;
#pragma unroll
  for (int i2 = 0; i2 < 8; ++i2) {
    const bf16x8_t pb = *(const bf16x8_t*)&eL[erow + i2 * 32 + 8 * g];
#pragma unroll
    for (int dt = 0; dt < 4; ++dt) {
      const bf16x8_t va = *(const bf16x8_t*)(vfb + ((size_t)i2 * 4 + dt) * 512);
      oacc[dt] = __builtin_amdgcn_mfma_f32_16x16x32_bf16(va, pb, oacc[dt], 0, 0, 0);
    }
#pragma unroll
    for (int qq = 0; qq < 2; ++qq) {
      const int q = i2 * 2 + qq;
      const float iq = invL[w * 16 + q];
      const bf16x4_t e4 = *(const bf16x4_t*)&eL[(w * 16 + q) * 264 + l * 4];
      f32x4_t p4;
      p4[0] = (float)e4[0] * iq;
      p4[1] = (float)e4[1] * iq;
      p4[2] = (float)e4[2] * iq;
      p4[3] = (float)e4[3] * iq;
      __builtin_nontemporal_store(p4, (f32x4_t*)(abase + (size_t)q * TT));
    }
  }
#pragma unroll
  for (int dt = 0; dt < 4; ++dt) {
    oacc[dt][0] *= inv; oacc[dt][1] *= inv;
    oacc[dt][2] *= inv; oacc[dt][3] *= inv;
  }

  // ---- all eL reads must complete block-wide before obuf overlays eL ----
  __syncthreads();

#pragma unroll
  for (int dt = 0; dt < 4; ++dt)
    *(f32x4_t*)&obuf[w * 1088 + ql * 68 + dt * 16 + 4 * g] = oacc[dt];
  __syncthreads();

  // ---- epilogue (wave 0): reduce + band-V MFMA + store attn ----
  if (w == 0) {
    f32x4_t osum[4];
#pragma unroll
    for (int dt = 0; dt < 4; ++dt) {
      const int off = ql * 68 + dt * 16 + 4 * g;
      osum[dt] = *(const f32x4_t*)&obuf[off] + *(const f32x4_t*)&obuf[1088 + off] +
                 *(const f32x4_t*)&obuf[2176 + off] + *(const f32x4_t*)&obuf[3264 + off];
    }
    const f32x4_t b0 = *(const f32x4_t*)&bandP[ql * 36 + g * 8];
    const f32x4_t b1 = *(const f32x4_t*)&bandP[ql * 36 + g * 8 + 4];
    bf16x8_t pbb;
#pragma unroll
    for (int i = 0; i < 4; ++i) {
      pbb[i] = (__bf16)b0[i];
      pbb[4 + i] = (__bf16)b1[i];
    }
#pragma unroll
    for (int dt = 0; dt < 4; ++dt) {
      bf16x8_t wa;
#pragma unroll
      for (int jj = 0; jj < 8; ++jj) {
        const int j = g * 8 + jj;
        wa[jj] = (__bf16)((j < 9) ? wV[j * HD + dt * 16 + ql] : 0.f);
      }
      osum[dt] = __builtin_amdgcn_mfma_f32_16x16x32_bf16(wa, pbb, osum[dt], 0, 0, 0);
    }
#pragma unroll
    for (int dt = 0; dt < 4; ++dt)
#pragma unroll
      for (int r = 0; r < 4; ++r)
        stg[(dt * 16 + 4 * g + r) * 17 + ql] = osum[dt][r];
    bf16x8_t o0, o1;
#pragma unroll
    for (int i = 0; i < 8; ++i) {
      o0[i] = (__bf16)stg[l * 17 + i];
      o1[i] = (__bf16)stg[l * 17 + 8 + i];
    }
    bf16* dp = attnw + ((size_t)b * CC + h * HD + l) * TT + q0;
    *(bf16x8_t*)dp = o0;
    *(bf16x8_t*)(dp + 8) = o1;
  }
}

extern "C" void kernel_launch(void* const* d_in, const int* in_sizes, int n_in,
                              void* d_out, int out_size, void* d_ws, size_t ws_size,
                              hipStream_t stream) {
  const float* X  = (const float*)d_in[0];
  const float* Wq = (const float*)d_in[1];
  const float* bq = (const float*)d_in[2];
  const float* Wk = (const float*)d_in[3];
  const float* bk = (const float*)d_in[4];
  const float* Wv = (const float*)d_in[5];
  const float* bv = (const float*)d_in[6];
  const float* Wp = (const float*)d_in[7];
  const float* bp = (const float*)d_in[8];
  const float* wK = (const float*)d_in[9];
  const float* wV = (const float*)d_in[10];

  float* out       = (float*)d_out;
  float* align_out = out + (size_t)BB * NCOUT * TT;

  const size_t SZ = (size_t)BB * HH * TT * HD;
  bf16* qw    = (bf16*)d_ws;
  bf16* kfrag = qw + SZ;
  bf16* vfrag = qw + 2 * SZ;
  bf16* attnw = qw + 3 * SZ;

  gemm_qkv<<<dim3(TT / 64, 24, BB), 256, 0, stream>>>(
      X, Wq, bq, Wk, bk, Wv, bv, qw, kfrag, vfrag);
  attn_v11<<<dim3(4096), 256, 0, stream>>>(
      qw, kfrag, vfrag, wK, wV, align_out, attnw);
  gemm_out<<<dim3(TT / 64, NCOUT / 64, BB), 256, 0, stream>>>(
      attnw, Wp, bp, out);
}

// Round 15
// 144.315 us; speedup vs baseline: 1.7241x; 1.2736x over previous
//
#include <hip/hip_runtime.h>
#include <hip/hip_bf16.h>

#define BB 8
#define CC 512
#define TT 1024
#define HH 8
#define HD 64
#define CLIPW 4
#define NCOUT 512

using bf16 = __hip_bfloat16;
typedef __bf16 bf16x8_t __attribute__((ext_vector_type(8)));
typedef __bf16 bf16x4_t __attribute__((ext_vector_type(4)));
typedef float f32x4_t __attribute__((ext_vector_type(4)));

// ===========================================================================
// prep_w: W (512x512 fp32, row-major [o][c]) -> A-frag bf16 layout
//   wf[(ot*16 + ct)*512 + l*8 + j] = W[ot*16 + (l&15)][ct*32 + (l>>4)*8 + j]
// ===========================================================================
__global__ __launch_bounds__(256) void prep_w(
    const float* __restrict__ Wq, const float* __restrict__ Wk,
    const float* __restrict__ Wv, const float* __restrict__ Wp,
    bf16* __restrict__ wqf, bf16* __restrict__ wkf,
    bf16* __restrict__ wvf, bf16* __restrict__ wpf) {
  const int which = blockIdx.y;
  const float* W = (which == 0) ? Wq : (which == 1) ? Wk : (which == 2) ? Wv : Wp;
  bf16* F = (which == 0) ? wqf : (which == 1) ? wkf : (which == 2) ? wvf : wpf;
  const int gid = blockIdx.x * 256 + threadIdx.x;
  const int l = gid & 63;
  const int fid = gid >> 6;            // ot*16 + ct, 0..511
  const int ct = fid & 15, ot = fid >> 4;
  const int sl = l & 15, g = l >> 4;
  const float* src = W + (size_t)(ot * 16 + sl) * CC + ct * 32 + g * 8;
  bf16x8_t p;
#pragma unroll
  for (int j = 0; j < 8; ++j) p[j] = (__bf16)src[j];
  *(bf16x8_t*)(F + (size_t)fid * 512 + l * 8) = p;
}

// ===========================================================================
// prep_x: X [b][c][t] fp32 -> B-frag bf16 layout
//   xfrag[((b*64 + tt)*16 + ct)*512 + l*8 + j] = X[b][ct*32+(l>>4)*8+j][tt*16+(l&15)]
// ===========================================================================
__global__ __launch_bounds__(256) void prep_x(
    const float* __restrict__ X, bf16* __restrict__ xfrag) {
  __shared__ float Xs[32][72];
  const int b = blockIdx.z, ct = blockIdx.y, tq = blockIdx.x;
  const int c0 = ct * 32, t0 = tq * 64;
  const int tid = threadIdx.x;
  {
    const int ci = tid >> 4;           // 0..15
    const int t4 = (tid & 15) * 4;
#pragma unroll
    for (int cp = 0; cp < 2; ++cp) {
      const int c = cp * 16 + ci;
      const float4 x4 = *(const float4*)&X[((size_t)b * CC + c0 + c) * TT + t0 + t4];
      *(float4*)&Xs[c][t4] = x4;
    }
  }
  __syncthreads();
  const int l = tid & 63, fr = tid >> 6;   // fr = local tt (0..3)
  const int sl = l & 15, g = l >> 4;
  bf16x8_t p;
#pragma unroll
  for (int j = 0; j < 8; ++j) p[j] = (__bf16)Xs[g * 8 + j][fr * 16 + sl];
  *(bf16x8_t*)(xfrag + (((size_t)b * 64 + tq * 4 + fr) * 16 + ct) * 512 + l * 8) = p;
}

// ===========================================================================
// gemm_qkv2: zero-LDS main loop from frag operands.
// m==0 -> qfrag (B-frag layout for attn), m==1 -> kfrag, m==2 -> vfrag.
// ===========================================================================
__global__ __launch_bounds__(256) void gemm_qkv2(
    const bf16* __restrict__ xfrag,
    const bf16* __restrict__ wqf, const bf16* __restrict__ wkf,
    const bf16* __restrict__ wvf,
    const float* __restrict__ bq, const float* __restrict__ bk,
    const float* __restrict__ bv,
    bf16* __restrict__ qfrag, bf16* __restrict__ kfrag, bf16* __restrict__ vfrag) {
  __shared__ __align__(16) float Cs[64 * 68];
  const int y  = blockIdx.y;
  const int m  = y >> 3;
  const int o0 = (y & 7) * 64;
  const int t0 = blockIdx.x * 64;
  const int b  = blockIdx.z;
  const bf16* WF = (m == 0) ? wqf : (m == 1) ? wkf : wvf;
  const float* bias = (m == 0) ? bq : (m == 1) ? bk : bv;

  const int tid = threadIdx.x;
  const int w = tid >> 6, l = tid & 63, g = l >> 4, sl = l & 15;
  const int wr = w >> 1, wc = w & 1;
  const int ot0 = (o0 >> 4) + wr * 2;
  const int tt0 = (t0 >> 4) + wc * 2;

  f32x4_t acc[2][2] = {};
#pragma unroll 4
  for (int ct = 0; ct < 16; ++ct) {
    bf16x8_t a[2], bb[2];
#pragma unroll
    for (int mm = 0; mm < 2; ++mm)
      a[mm] = *(const bf16x8_t*)(WF + ((size_t)(ot0 + mm) * 16 + ct) * 512 + l * 8);
#pragma unroll
    for (int nn = 0; nn < 2; ++nn)
      bb[nn] = *(const bf16x8_t*)(xfrag + (((size_t)b * 64 + tt0 + nn) * 16 + ct) * 512 + l * 8);
#pragma unroll
    for (int mm = 0; mm < 2; ++mm)
#pragma unroll
      for (int nn = 0; nn < 2; ++nn)
        acc[mm][nn] = __builtin_amdgcn_mfma_f32_16x16x32_bf16(a[mm], bb[nn], acc[mm][nn], 0, 0, 0);
  }

#pragma unroll
  for (int mm = 0; mm < 2; ++mm)
#pragma unroll
    for (int nn = 0; nn < 2; ++nn)
#pragma unroll
      for (int r = 0; r < 4; ++r)
        Cs[(wr * 32 + mm * 16 + 4 * g + r) * 68 + wc * 32 + nn * 16 + sl] = acc[mm][nn][r];
  __syncthreads();

  const int hh2 = o0 >> 6;
  const int bh  = b * HH + hh2;
  const int fr = tid >> 6, l2 = tid & 63;
  const int sl2 = l2 & 15, g2 = l2 >> 4;
  if (m == 0) {
    // qfrag: B-frag layout [bh][qt][kh][lane][8]
#pragma unroll
    for (int kh = 0; kh < 2; ++kh) {
      bf16x8_t p;
#pragma unroll
      for (int j = 0; j < 8; ++j) {
        const int d = kh * 32 + g2 * 8 + j;
        p[j] = (__bf16)(Cs[d * 68 + fr * 16 + sl2] + bias[o0 + d]);
      }
      *(bf16x8_t*)(qfrag + (((size_t)bh * 64 + (t0 >> 4) + fr) * 2 + kh) * 512 + l2 * 8) = p;
    }
  } else if (m == 1) {
    bf16* dpf = kfrag + (((size_t)bh * 64 + (t0 >> 4) + fr) * 2) * 512;
#pragma unroll
    for (int half = 0; half < 2; ++half) {
      bf16x8_t p;
#pragma unroll
      for (int j = 0; j < 8; ++j) {
        const int d = half * 32 + g2 * 8 + j;
        p[j] = (__bf16)(Cs[d * 68 + fr * 16 + sl2] + bias[o0 + d]);
      }
      *(bf16x8_t*)(dpf + half * 512 + l2 * 8) = p;
    }
  } else {
    const int dt = fr;                  // 0..3
    const int d  = dt * 16 + sl2;
    const float bv_ = bias[o0 + d];
#pragma unroll
    for (int i2p = 0; i2p < 2; ++i2p) {
      const int i2 = (t0 >> 5) + i2p;
      bf16x8_t p;
#pragma unroll
      for (int j = 0; j < 8; ++j) {
        const int tloc = i2p * 32 + g2 * 8 + j;
        p[j] = (__bf16)(Cs[d * 68 + tloc] + bv_);
      }
      *(bf16x8_t*)(vfrag + ((((size_t)bh * 32 + i2) * 4 + dt) * 64 + l2) * 8) = p;
    }
  }
}

// ===========================================================================
// gemm_out2: zero-LDS main loop; A = wpf frags, B = attnfrag; fp32 out [o][t].
// ===========================================================================
__global__ __launch_bounds__(256) void gemm_out2(
    const bf16* __restrict__ attnfrag, const bf16* __restrict__ wpf,
    const float* __restrict__ bp, float* __restrict__ out) {
  __shared__ __align__(16) float Cs[64 * 68];
  const int o0 = blockIdx.y * 64;
  const int t0 = blockIdx.x * 64;
  const int b  = blockIdx.z;
  const int tid = threadIdx.x;
  const int w = tid >> 6, l = tid & 63, g = l >> 4, sl = l & 15;
  const int wr = w >> 1, wc = w & 1;
  const int ot0 = (o0 >> 4) + wr * 2;
  const int tt0 = (t0 >> 4) + wc * 2;

  f32x4_t acc[2][2] = {};
#pragma unroll 4
  for (int ct = 0; ct < 16; ++ct) {
    bf16x8_t a[2], bb[2];
#pragma unroll
    for (int mm = 0; mm < 2; ++mm)
      a[mm] = *(const bf16x8_t*)(wpf + ((size_t)(ot0 + mm) * 16 + ct) * 512 + l * 8);
#pragma unroll
    for (int nn = 0; nn < 2; ++nn)
      bb[nn] = *(const bf16x8_t*)(attnfrag + (((size_t)b * 64 + tt0 + nn) * 16 + ct) * 512 + l * 8);
#pragma unroll
    for (int mm = 0; mm < 2; ++mm)
#pragma unroll
      for (int nn = 0; nn < 2; ++nn)
        acc[mm][nn] = __builtin_amdgcn_mfma_f32_16x16x32_bf16(a[mm], bb[nn], acc[mm][nn], 0, 0, 0);
  }

#pragma unroll
  for (int mm = 0; mm < 2; ++mm)
#pragma unroll
    for (int nn = 0; nn < 2; ++nn)
#pragma unroll
      for (int r = 0; r < 4; ++r)
        Cs[(wr * 32 + mm * 16 + 4 * g + r) * 68 + wc * 32 + nn * 16 + sl] = acc[mm][nn][r];
  __syncthreads();

  const int o = tid >> 2, tq = tid & 3;
  const float bv_ = bp[o0 + o];
  float* dp = out + ((size_t)b * NCOUT + o0 + o) * TT + t0 + tq * 16;
#pragma unroll
  for (int i4 = 0; i4 < 4; ++i4) {
    f32x4_t v = *(const f32x4_t*)&Cs[o * 68 + tq * 16 + i4 * 4];
    v[0] += bv_; v[1] += bv_; v[2] += bv_; v[3] += bv_;
    *(f32x4_t*)(dp + i4 * 4) = v;
  }
}

// ===========================================================================
// attn v12 = v11 with (a) Q read from qfrag (contiguous), (b) epilogue writes
// attnfrag (B-frag layout) instead of row-major attnw.
// ===========================================================================
__global__ __launch_bounds__(256, 4) void attn_v12(
    const bf16* __restrict__ qfrag, const bf16* __restrict__ kfrag,
    const bf16* __restrict__ vfrag,
    const float* __restrict__ wK, const float* __restrict__ wV,
    float* __restrict__ align_out, bf16* __restrict__ attnfrag) {
  const int fi   = blockIdx.x;
  const int xcd  = fi & 7;
  const int k2   = fi >> 3;
  const int bh   = ((k2 >> 6) << 3) + xcd;
  const int qblk = k2 & 63;
  const int b = bh >> 3, h = bh & 7;
  const int q0 = qblk * 16;

  const int tid = threadIdx.x;
  const int w = tid >> 6, l = tid & 63, g = l >> 4, ql = l & 15;
  const int qabs  = q0 + ql;
  const int sbase = w * 256;

  __shared__ __align__(16) char smem[39424];
  __bf16* eL    = (__bf16*)smem;
  float* bandv  = (float*)(smem + 33792);
  float* bandP  = (float*)(smem + 36864);
  float* redbuf = (float*)(smem + 39168);
  float* invL   = (float*)(smem + 33792);       // overlays bandv (free after p1)
  float* obuf   = (float*)smem;                 // overlay after barrier
  float* stg    = (float*)(smem + 17408);       // overlay epilogue

  for (int i = tid; i < 576; i += 256) bandP[i] = 0.f;

  // Q B-frags (contiguous 1KB wave loads)
  const bf16* qfb = qfrag + (((size_t)bh * 64 + (q0 >> 4)) * 2) * 512 + l * 8;
  const bf16x8_t qa0 = *(const bf16x8_t*)qfb;
  const bf16x8_t qa1 = *(const bf16x8_t*)(qfb + 512);

  // band-K: D[j][q] via mfma(A=wK rows, B=Q cols)
  {
    const int j = (ql < 9) ? ql : 0;
    const float* wkr = wK + j * HD + g * 8;
    const f32x4_t w0 = *(const f32x4_t*)wkr;
    const f32x4_t w1 = *(const f32x4_t*)(wkr + 4);
    const f32x4_t w2 = *(const f32x4_t*)(wkr + 32);
    const f32x4_t w3 = *(const f32x4_t*)(wkr + 36);
    bf16x8_t ka0, ka1;
#pragma unroll
    for (int i = 0; i < 4; ++i) {
      ka0[i] = (__bf16)w0[i]; ka0[4 + i] = (__bf16)w1[i];
      ka1[i] = (__bf16)w2[i]; ka1[4 + i] = (__bf16)w3[i];
    }
    f32x4_t bacc = {0.f, 0.f, 0.f, 0.f};
    bacc = __builtin_amdgcn_mfma_f32_16x16x32_bf16(ka0, qa0, bacc, 0, 0, 0);
    bacc = __builtin_amdgcn_mfma_f32_16x16x32_bf16(ka1, qa1, bacc, 0, 0, 0);
#pragma unroll
    for (int r = 0; r < 4; ++r)
      if (4 * g + r < 9) bandv[(w * 16 + ql) * 12 + 4 * g + r] = bacc[r];
  }

  // ---- pass 1: QK + exp; stash regs + k-major eL ----
  float ls = 0.f;
  bf16x4_t stash[16];
  const int erow = (w * 16 + ql) * 264;
  const bf16* kfb = kfrag + (((size_t)bh * 64 + w * 16) * 2) * 512 + l * 8;
#pragma unroll
  for (int st = 0; st < 16; ++st) {
    const bf16x8_t k0 = *(const bf16x8_t*)(kfb + (size_t)st * 1024);
    const bf16x8_t k1 = *(const bf16x8_t*)(kfb + (size_t)st * 1024 + 512);
    f32x4_t a = {0.f, 0.f, 0.f, 0.f};
    a = __builtin_amdgcn_mfma_f32_16x16x32_bf16(k0, qa0, a, 0, 0, 0);
    a = __builtin_amdgcn_mfma_f32_16x16x32_bf16(k1, qa1, a, 0, 0, 0);
    const int s0t = sbase + st * 16;
    const bool near = (s0t + 15 >= q0 - CLIPW) && (s0t <= q0 + 15 + CLIPW);
#pragma unroll
    for (int r = 0; r < 4; ++r) {
      float x = a[r];
      if (near) {
        const int delta = s0t + 4 * g + r - qabs;
        if ((unsigned)(delta + CLIPW) <= 2 * CLIPW)
          x += bandv[(w * 16 + ql) * 12 + delta + CLIPW];
      }
      const float e = __expf(x * 0.125f);
      stash[st][r] = (__bf16)e;
      ls += e;
    }
    *(bf16x4_t*)&eL[erow + st * 16 + 4 * g] = stash[st];
  }
  ls += __shfl_xor(ls, 16);
  ls += __shfl_xor(ls, 32);
  if (l < 16) redbuf[w * 16 + ql] = ls;
  __syncthreads();
  const float inv = 1.0f / (redbuf[ql] + redbuf[16 + ql] + redbuf[32 + ql] + redbuf[48 + ql]);
  if (l < 16) invL[w * 16 + l] = inv;

  // ---- bandP extraction (predicated, mostly skipped) ----
#pragma unroll
  for (int st = 0; st < 16; ++st) {
    const int s0t = sbase + st * 16;
    const bool near = (s0t + 15 >= q0 - CLIPW) && (s0t <= q0 + 15 + CLIPW);
    if (near) {
#pragma unroll
      for (int r = 0; r < 4; ++r) {
        const int delta = s0t + 4 * g + r - qabs;
        if ((unsigned)(delta + CLIPW) <= 2 * CLIPW)
          bandP[ql * 36 + delta + CLIPW] = (float)stash[st][r] * inv;
      }
    }
  }

  // ---- pass 2: PV + interleaved dense align stores (2 q-rows / iter) ----
  f32x4_t oacc[4] = {};
  const bf16* vfb = vfrag + (((size_t)bh * 32 + w * 8) * 4) * 512 + l * 8;
  float* abase = align_out + ((size_t)bh * TT + q0) * TT + sbase + l * 4;
#pragma unroll
  for (int i2 = 0; i2 < 8; ++i2) {
    const bf16x8_t pb = *(const bf16x8_t*)&eL[erow + i2 * 32 + 8 * g];
#pragma unroll
    for (int dt = 0; dt < 4; ++dt) {
      const bf16x8_t va = *(const bf16x8_t*)(vfb + ((size_t)i2 * 4 + dt) * 512);
      oacc[dt] = __builtin_amdgcn_mfma_f32_16x16x32_bf16(va, pb, oacc[dt], 0, 0, 0);
    }
#pragma unroll
    for (int qq = 0; qq < 2; ++qq) {
      const int q = i2 * 2 + qq;
      const float iq = invL[w * 16 + q];
      const bf16x4_t e4 = *(const bf16x4_t*)&eL[(w * 16 + q) * 264 + l * 4];
      f32x4_t p4;
      p4[0] = (float)e4[0] * iq;
      p4[1] = (float)e4[1] * iq;
      p4[2] = (float)e4[2] * iq;
      p4[3] = (float)e4[3] * iq;
      __builtin_nontemporal_store(p4, (f32x4_t*)(abase + (size_t)q * TT));
    }
  }
#pragma unroll
  for (int dt = 0; dt < 4; ++dt) {
    oacc[dt][0] *= inv; oacc[dt][1] *= inv;
    oacc[dt][2] *= inv; oacc[dt][3] *= inv;
  }

  // ---- all eL reads must complete block-wide before obuf overlays eL ----
  __syncthreads();

#pragma unroll
  for (int dt = 0; dt < 4; ++dt)
    *(f32x4_t*)&obuf[w * 1088 + ql * 68 + dt * 16 + 4 * g] = oacc[dt];
  __syncthreads();

  // ---- epilogue (wave 0): reduce + band-V MFMA + frag-layout attn store ----
  if (w == 0) {
    f32x4_t osum[4];
#pragma unroll
    for (int dt = 0; dt < 4; ++dt) {
      const int off = ql * 68 + dt * 16 + 4 * g;
      osum[dt] = *(const f32x4_t*)&obuf[off] + *(const f32x4_t*)&obuf[1088 + off] +
                 *(const f32x4_t*)&obuf[2176 + off] + *(const f32x4_t*)&obuf[3264 + off];
    }
    const f32x4_t b0 = *(const f32x4_t*)&bandP[ql * 36 + g * 8];
    const f32x4_t b1 = *(const f32x4_t*)&bandP[ql * 36 + g * 8 + 4];
    bf16x8_t pbb;
#pragma unroll
    for (int i = 0; i < 4; ++i) {
      pbb[i] = (__bf16)b0[i];
      pbb[4 + i] = (__bf16)b1[i];
    }
#pragma unroll
    for (int dt = 0; dt < 4; ++dt) {
      bf16x8_t wa;
#pragma unroll
      for (int jj = 0; jj < 8; ++jj) {
        const int j = g * 8 + jj;
        wa[jj] = (__bf16)((j < 9) ? wV[j * HD + dt * 16 + ql] : 0.f);
      }
      osum[dt] = __builtin_amdgcn_mfma_f32_16x16x32_bf16(wa, pbb, osum[dt], 0, 0, 0);
    }
#pragma unroll
    for (int dt = 0; dt < 4; ++dt)
#pragma unroll
      for (int r = 0; r < 4; ++r)
        stg[(dt * 16 + 4 * g + r) * 17 + ql] = osum[dt][r];
    // attnfrag write: ct global = h*2 + ctl, tt = q0>>4
#pragma unroll
    for (int ctl = 0; ctl < 2; ++ctl) {
      bf16x8_t p;
#pragma unroll
      for (int j = 0; j < 8; ++j)
        p[j] = (__bf16)stg[(ctl * 32 + g * 8 + j) * 17 + ql];
      *(bf16x8_t*)(attnfrag +
                   (((size_t)b * 64 + (q0 >> 4)) * 16 + h * 2 + ctl) * 512 + l * 8) = p;
    }
  }
}

extern "C" void kernel_launch(void* const* d_in, const int* in_sizes, int n_in,
                              void* d_out, int out_size, void* d_ws, size_t ws_size,
                              hipStream_t stream) {
  const float* X  = (const float*)d_in[0];
  const float* Wq = (const float*)d_in[1];
  const float* bq = (const float*)d_in[2];
  const float* Wk = (const float*)d_in[3];
  const float* bk = (const float*)d_in[4];
  const float* Wv = (const float*)d_in[5];
  const float* bv = (const float*)d_in[6];
  const float* Wp = (const float*)d_in[7];
  const float* bp = (const float*)d_in[8];
  const float* wK = (const float*)d_in[9];
  const float* wV = (const float*)d_in[10];

  float* out       = (float*)d_out;
  float* align_out = out + (size_t)BB * NCOUT * TT;

  const size_t SZ = (size_t)BB * HH * TT * HD;   // 4,194,304 elems (8 MB bf16)
  const size_t WF = 512 * 512;                    // 262,144 elems (0.5 MB bf16)
  bf16* qfrag    = (bf16*)d_ws;
  bf16* kfrag    = qfrag + SZ;
  bf16* vfrag    = qfrag + 2 * SZ;
  bf16* attnfrag = qfrag + 3 * SZ;
  bf16* xfrag    = qfrag + 4 * SZ;
  bf16* wqf      = qfrag + 5 * SZ;
  bf16* wkf      = wqf + WF;
  bf16* wvf      = wkf + WF;
  bf16* wpf      = wvf + WF;

  prep_w<<<dim3(128, 4), 256, 0, stream>>>(Wq, Wk, Wv, Wp, wqf, wkf, wvf, wpf);
  prep_x<<<dim3(16, 16, BB), 256, 0, stream>>>(X, xfrag);
  gemm_qkv2<<<dim3(16, 24, BB), 256, 0, stream>>>(
      xfrag, wqf, wkf, wvf, bq, bk, bv, qfrag, kfrag, vfrag);
  attn_v12<<<dim3(4096), 256, 0, stream>>>(
      qfrag, kfrag, vfrag, wK, wV, align_out, attnfrag);
  gemm_out2<<<dim3(16, 8, BB), 256, 0, stream>>>(attnfrag, wpf, bp, out);
}